// Round 1
// baseline (2634.346 us; speedup 1.0000x reference)
//
#include <hip/hip_runtime.h>
#include <math.h>

#define NNODES 20000
#define NEDGES 160000
#define HIDDIM 128
#define NHEADS 8
#define NGRAPH 64

// ---------------- utility ----------------
__global__ __launch_bounds__(256) void zero_kernel(float* __restrict__ p, int n) {
    int i = blockIdx.x * blockDim.x + threadIdx.x;
    if (i < n) p[i] = 0.f;
}

// ---------------- CSR build ----------------
__global__ __launch_bounds__(256) void count_deg_kernel(const int* __restrict__ dst,
                                                        int* __restrict__ deg, int e) {
    int i = blockIdx.x * blockDim.x + threadIdx.x;
    if (i < e) atomicAdd(&deg[dst[i]], 1);
}

__global__ __launch_bounds__(1024) void scan_kernel(const int* __restrict__ deg,
                                                    int* __restrict__ offs, int n) {
    __shared__ int buf[1024];
    __shared__ int carry;
    int t = threadIdx.x;
    if (t == 0) { carry = 0; offs[0] = 0; }
    __syncthreads();
    for (int base = 0; base < n; base += 1024) {
        int i = base + t;
        int val = (i < n) ? deg[i] : 0;
        buf[t] = val;
        __syncthreads();
        for (int off = 1; off < 1024; off <<= 1) {
            int tmp = (t >= off) ? buf[t - off] : 0;
            __syncthreads();
            buf[t] += tmp;
            __syncthreads();
        }
        int c = carry;
        if (i < n) offs[i + 1] = c + buf[t];
        __syncthreads();
        if (t == 0) carry = c + buf[1023];
        __syncthreads();
    }
}

__global__ __launch_bounds__(256) void scatter_kernel(const int* __restrict__ src,
                                                      const int* __restrict__ dst,
                                                      const int* __restrict__ offs,
                                                      int* __restrict__ cursor,
                                                      int* __restrict__ csr_src, int e) {
    int i = blockIdx.x * blockDim.x + threadIdx.x;
    if (i < e) {
        int d = dst[i];
        int pos = offs[d] + atomicAdd(&cursor[d], 1);
        csr_src[pos] = src[i];
    }
}

// ---------------- GEMM: C[i,t] = sum_k A[i,k]*W[k, t] + bias[t], K=128, M=128 ----------------
// one block (128 threads) per row; W leading dim ldw (128 or 1024 w/ column offset applied by caller)
__global__ __launch_bounds__(128) void gemm128_kernel(const float* __restrict__ A,
                                                      const float* __restrict__ W,
                                                      const float* __restrict__ bias,
                                                      float* __restrict__ C, int ldw) {
    __shared__ float arow[HIDDIM];
    int i = blockIdx.x;
    int t = threadIdx.x;
    arow[t] = A[i * HIDDIM + t];
    __syncthreads();
    float acc = bias[t];
#pragma unroll 32
    for (int kk = 0; kk < HIDDIM; ++kk)
        acc = fmaf(arow[kk], W[kk * ldw + t], acc);
    C[i * HIDDIM + t] = acc;
}

// ---------------- attention layers 0-2 (8 heads x d=16, concat) + beta gate fused ----------------
__global__ __launch_bounds__(128) void attn_small_kernel(
    const float* __restrict__ q, const float* __restrict__ k, const float* __restrict__ v,
    const float* __restrict__ s, const float* __restrict__ Wb,
    const int* __restrict__ offs, const int* __restrict__ csr_src,
    float* __restrict__ out) {
    int i = blockIdx.x;
    int t = threadIdx.x;  // t = head*16 + dim
    float qt = q[i * HIDDIM + t];
    int e0 = offs[i], e1 = offs[i + 1];
    float m = -1e30f, l = 0.f, acc = 0.f;
    for (int e = e0; e < e1; ++e) {
        int sn = csr_src[e];
        float kt = k[sn * HIDDIM + t];
        float vt = v[sn * HIDDIM + t];
        float p = qt * kt;
        p += __shfl_xor(p, 1);
        p += __shfl_xor(p, 2);
        p += __shfl_xor(p, 4);
        p += __shfl_xor(p, 8);          // dot over the 16 lanes of this head
        float logit = p * 0.25f;        // 1/sqrt(16)
        float mnew = fmaxf(m, logit);
        float sc = __expf(m - mnew);
        float w = __expf(logit - mnew);
        acc = acc * sc + w * vt;
        l = l * sc + w;
        m = mnew;
    }
    float o = acc / (l + 1e-16f);
    // beta gate: g = sigmoid([o, r, o-r] @ Wb)
    float r = s[i * HIDDIM + t];
    float part = o * Wb[t] + r * Wb[HIDDIM + t] + (o - r) * Wb[2 * HIDDIM + t];
#pragma unroll
    for (int msk = 1; msk <= 32; msk <<= 1) part += __shfl_xor(part, msk);
    __shared__ float wsum[2];
    if ((t & 63) == 0) wsum[t >> 6] = part;
    __syncthreads();
    float tot = wsum[0] + wsum[1];
    float g = 1.f / (1.f + __expf(-tot));
    out[i * HIDDIM + t] = g * r + (1.f - g) * o;
}

// ---------------- attention layer 3, one head (d=128), accumulates into outacc ----------------
__global__ __launch_bounds__(128) void attn_big_kernel(
    const float* __restrict__ q, const float* __restrict__ k, const float* __restrict__ v,
    const int* __restrict__ offs, const int* __restrict__ csr_src,
    float* __restrict__ outacc) {
    int i = blockIdx.x;
    int t = threadIdx.x;
    float qt = q[i * HIDDIM + t];
    int e0 = offs[i], e1 = offs[i + 1];
    __shared__ float red[2];
    float m = -1e30f, l = 0.f, acc = 0.f;
    for (int e = e0; e < e1; ++e) {
        int sn = csr_src[e];
        float kt = k[sn * HIDDIM + t];
        float vt = v[sn * HIDDIM + t];
        float p = qt * kt;
#pragma unroll
        for (int msk = 1; msk <= 32; msk <<= 1) p += __shfl_xor(p, msk);
        if ((t & 63) == 0) red[t >> 6] = p;
        __syncthreads();
        float logit = (red[0] + red[1]) * 0.08838834764831845f;  // 1/sqrt(128)
        __syncthreads();
        float mnew = fmaxf(m, logit);
        float sc = __expf(m - mnew);
        float w = __expf(logit - mnew);
        acc = acc * sc + w * vt;
        l = l * sc + w;
        m = mnew;
    }
    outacc[i * HIDDIM + t] += acc / (l + 1e-16f);
}

// ---------------- beta gate for layer 3 (out = mean over 8 heads already summed) ----------------
__global__ __launch_bounds__(128) void beta3_kernel(float* __restrict__ obuf,
                                                    const float* __restrict__ s,
                                                    const float* __restrict__ Wb) {
    int i = blockIdx.x, t = threadIdx.x;
    float o = obuf[i * HIDDIM + t] * 0.125f;  // mean over 8 heads
    float r = s[i * HIDDIM + t];
    float part = o * Wb[t] + r * Wb[HIDDIM + t] + (o - r) * Wb[2 * HIDDIM + t];
#pragma unroll
    for (int msk = 1; msk <= 32; msk <<= 1) part += __shfl_xor(part, msk);
    __shared__ float wsum[2];
    if ((t & 63) == 0) wsum[t >> 6] = part;
    __syncthreads();
    float tot = wsum[0] + wsum[1];
    float g = 1.f / (1.f + __expf(-tot));
    obuf[i * HIDDIM + t] = g * r + (1.f - g) * o;
}

// ---------------- batchnorm ----------------
__global__ __launch_bounds__(128) void bn_stats_kernel(const float* __restrict__ x,
                                                       float* __restrict__ stat, int n) {
    int t = threadIdx.x;
    float s = 0.f, sq = 0.f;
    for (int i = blockIdx.x; i < n; i += gridDim.x) {
        float v = x[i * HIDDIM + t];
        s += v;
        sq += v * v;
    }
    atomicAdd(&stat[t], s);
    atomicAdd(&stat[HIDDIM + t], sq);
}

__global__ __launch_bounds__(128) void bn_apply_kernel(float* __restrict__ x,
                                                       const float* __restrict__ stat,
                                                       const float* __restrict__ gamma,
                                                       const float* __restrict__ beta, int n) {
    int t = threadIdx.x;
    float mu = stat[t] / (float)n;
    float var = stat[HIDDIM + t] / (float)n - mu * mu;
    float rs = rsqrtf(var + 1e-5f);
    float g = gamma[t], b = beta[t];
    for (int i = blockIdx.x; i < n; i += gridDim.x) {
        float v = x[i * HIDDIM + t];
        v = (v - mu) * rs * g + b;
        x[i * HIDDIM + t] = fmaxf(v, 0.f);
    }
}

// ---------------- global mean pool ----------------
__global__ __launch_bounds__(128) void pool_sum_kernel(const float* __restrict__ x,
                                                       const int* __restrict__ batch,
                                                       float* __restrict__ out,
                                                       float* __restrict__ cnt) {
    int i = blockIdx.x, t = threadIdx.x;
    int b = batch[i];
    atomicAdd(&out[b * HIDDIM + t], x[i * HIDDIM + t]);
    if (t == 0) atomicAdd(&cnt[b], 1.f);
}

__global__ __launch_bounds__(128) void pool_div_kernel(float* __restrict__ out,
                                                       const float* __restrict__ cnt) {
    int g = blockIdx.x, t = threadIdx.x;
    out[g * HIDDIM + t] /= fmaxf(cnt[g], 1.f);
}

// ---------------- host ----------------
extern "C" void kernel_launch(void* const* d_in, const int* in_sizes, int n_in,
                              void* d_out, int out_size, void* d_ws, size_t ws_size,
                              hipStream_t stream) {
    const float* x       = (const float*)d_in[0];
    const int*   ei      = (const int*)d_in[1];
    const int*   batch   = (const int*)d_in[2];
    const float* Wp      = (const float*)d_in[3];
    const float* bp      = (const float*)d_in[4];
    const float* Wq      = (const float*)d_in[5];
    const float* bq      = (const float*)d_in[6];
    const float* Wk      = (const float*)d_in[7];
    const float* bk      = (const float*)d_in[8];
    const float* Wv      = (const float*)d_in[9];
    const float* bv      = (const float*)d_in[10];
    const float* Ws      = (const float*)d_in[11];
    const float* bs      = (const float*)d_in[12];
    const float* Wbeta   = (const float*)d_in[13];
    const float* Wq3     = (const float*)d_in[14];
    const float* bq3     = (const float*)d_in[15];
    const float* Wk3     = (const float*)d_in[16];
    const float* bk3     = (const float*)d_in[17];
    const float* Wv3     = (const float*)d_in[18];
    const float* bv3     = (const float*)d_in[19];
    const float* Ws3     = (const float*)d_in[20];
    const float* bs3     = (const float*)d_in[21];
    const float* Wbeta3  = (const float*)d_in[22];
    const float* bn_gamma = (const float*)d_in[23];
    const float* bn_beta  = (const float*)d_in[24];
    float* out = (float*)d_out;

    const int* esrc = ei;           // edge_index[0]
    const int* edst = ei + NEDGES;  // edge_index[1]

    // workspace carve-out (256B aligned)
    char* wp = (char*)d_ws;
    auto alloc = [&](size_t nbytes) -> char* {
        char* p = wp;
        wp += (nbytes + 255) & ~(size_t)255;
        return p;
    };
    float* hbuf   = (float*)alloc((size_t)NNODES * HIDDIM * 4);
    float* obuf   = (float*)alloc((size_t)NNODES * HIDDIM * 4);
    float* qb     = (float*)alloc((size_t)NNODES * HIDDIM * 4);
    float* kb     = (float*)alloc((size_t)NNODES * HIDDIM * 4);
    float* vb     = (float*)alloc((size_t)NNODES * HIDDIM * 4);
    float* sb     = (float*)alloc((size_t)NNODES * HIDDIM * 4);
    float* bnstat = (float*)alloc(2 * HIDDIM * 4);
    float* cnt    = (float*)alloc(NGRAPH * 4);
    int*   deg    = (int*)alloc(NNODES * 4);
    int*   cursor = (int*)alloc(NNODES * 4);
    int*   offs   = (int*)alloc((NNODES + 1) * 4);
    int*   csrsrc = (int*)alloc(NEDGES * 4);

    const int TB = 256;
    // ---- CSR build (edge_index is identical every call, but ws is re-poisoned) ----
    zero_kernel<<<(NNODES + TB - 1) / TB, TB, 0, stream>>>((float*)deg, NNODES);
    zero_kernel<<<(NNODES + TB - 1) / TB, TB, 0, stream>>>((float*)cursor, NNODES);
    count_deg_kernel<<<(NEDGES + TB - 1) / TB, TB, 0, stream>>>(edst, deg, NEDGES);
    scan_kernel<<<1, 1024, 0, stream>>>(deg, offs, NNODES);
    scatter_kernel<<<(NEDGES + TB - 1) / TB, TB, 0, stream>>>(esrc, edst, offs, cursor, csrsrc, NEDGES);

    // ---- initial projection ----
    gemm128_kernel<<<NNODES, 128, 0, stream>>>(x, Wp, bp, hbuf, HIDDIM);

    float* hcur = hbuf;
    float* hnxt = obuf;

    // ---- layers 0..2 ----
    for (int li = 0; li < 3; ++li) {
        const float* Wqi = Wq + (size_t)li * HIDDIM * HIDDIM;
        const float* Wki = Wk + (size_t)li * HIDDIM * HIDDIM;
        const float* Wvi = Wv + (size_t)li * HIDDIM * HIDDIM;
        const float* Wsi = Ws + (size_t)li * HIDDIM * HIDDIM;
        const float* bqi = bq + li * HIDDIM;
        const float* bki = bk + li * HIDDIM;
        const float* bvi = bv + li * HIDDIM;
        const float* bsi = bs + li * HIDDIM;
        const float* Wbi = Wbeta + li * 3 * HIDDIM;

        gemm128_kernel<<<NNODES, 128, 0, stream>>>(hcur, Wqi, bqi, qb, HIDDIM);
        gemm128_kernel<<<NNODES, 128, 0, stream>>>(hcur, Wki, bki, kb, HIDDIM);
        gemm128_kernel<<<NNODES, 128, 0, stream>>>(hcur, Wvi, bvi, vb, HIDDIM);
        gemm128_kernel<<<NNODES, 128, 0, stream>>>(hcur, Wsi, bsi, sb, HIDDIM);

        attn_small_kernel<<<NNODES, 128, 0, stream>>>(qb, kb, vb, sb, Wbi, offs, csrsrc, hnxt);

        zero_kernel<<<1, 256, 0, stream>>>(bnstat, 2 * HIDDIM);
        bn_stats_kernel<<<200, 128, 0, stream>>>(hnxt, bnstat, NNODES);
        bn_apply_kernel<<<256, 128, 0, stream>>>(hnxt, bnstat, bn_gamma + li * HIDDIM,
                                                 bn_beta + li * HIDDIM, NNODES);
        float* t2 = hcur; hcur = hnxt; hnxt = t2;
    }

    // ---- layer 3: 8 independent heads of d=128, mean-combined ----
    zero_kernel<<<(NNODES * HIDDIM + TB - 1) / TB, TB, 0, stream>>>(hnxt, NNODES * HIDDIM);
    for (int hd = 0; hd < NHEADS; ++hd) {
        gemm128_kernel<<<NNODES, 128, 0, stream>>>(hcur, Wq3 + hd * HIDDIM, bq3 + hd * HIDDIM, qb, NHEADS * HIDDIM);
        gemm128_kernel<<<NNODES, 128, 0, stream>>>(hcur, Wk3 + hd * HIDDIM, bk3 + hd * HIDDIM, kb, NHEADS * HIDDIM);
        gemm128_kernel<<<NNODES, 128, 0, stream>>>(hcur, Wv3 + hd * HIDDIM, bv3 + hd * HIDDIM, vb, NHEADS * HIDDIM);
        attn_big_kernel<<<NNODES, 128, 0, stream>>>(qb, kb, vb, offs, csrsrc, hnxt);
    }
    gemm128_kernel<<<NNODES, 128, 0, stream>>>(hcur, Ws3, bs3, sb, HIDDIM);
    beta3_kernel<<<NNODES, 128, 0, stream>>>(hnxt, sb, Wbeta3);
    zero_kernel<<<1, 256, 0, stream>>>(bnstat, 2 * HIDDIM);
    bn_stats_kernel<<<200, 128, 0, stream>>>(hnxt, bnstat, NNODES);
    bn_apply_kernel<<<256, 128, 0, stream>>>(hnxt, bnstat, bn_gamma + 3 * HIDDIM,
                                             bn_beta + 3 * HIDDIM, NNODES);

    // ---- global mean pool ----
    zero_kernel<<<(NGRAPH * HIDDIM + TB - 1) / TB, TB, 0, stream>>>(out, NGRAPH * HIDDIM);
    zero_kernel<<<1, NGRAPH, 0, stream>>>(cnt, NGRAPH);
    pool_sum_kernel<<<NNODES, 128, 0, stream>>>(hnxt, batch, out, cnt);
    pool_div_kernel<<<NGRAPH, 128, 0, stream>>>(out, cnt);
}

// Round 2
// 1423.490 us; speedup vs baseline: 1.8506x; 1.8506x over previous
//
#include <hip/hip_runtime.h>
#include <math.h>

#define NNODES 20000
#define NPAD   20032
#define NEDGES 160000
#define HIDDIM 128
#define NHEADS 8
#define NGRAPH 64
#define QS 512   // fused q|k|v|s row stride
#define KC 384   // concatenated K (hi | lo | hi)

typedef short short8 __attribute__((ext_vector_type(8)));
typedef float floatx4 __attribute__((ext_vector_type(4)));

__device__ inline unsigned short f2bf(float x) {
    unsigned u = __float_as_uint(x);
    u += 0x7fff + ((u >> 16) & 1);   // round-to-nearest-even
    return (unsigned short)(u >> 16);
}
__device__ inline float bf2f(unsigned short h) {
    return __uint_as_float(((unsigned)h) << 16);
}

// ---------------- utility ----------------
__global__ __launch_bounds__(256) void zero_kernel(float* __restrict__ p, int n) {
    int i = blockIdx.x * blockDim.x + threadIdx.x;
    if (i < n) p[i] = 0.f;
}

// ---------------- CSR build ----------------
__global__ __launch_bounds__(256) void count_deg_kernel(const int* __restrict__ dst,
                                                        int* __restrict__ deg, int e) {
    int i = blockIdx.x * blockDim.x + threadIdx.x;
    if (i < e) atomicAdd(&deg[dst[i]], 1);
}

__global__ __launch_bounds__(256) void scan1_kernel(const int* __restrict__ deg,
                                                    int* __restrict__ chunk,
                                                    int* __restrict__ bsum, int n) {
    __shared__ int buf[256];
    int t = threadIdx.x;
    int i = blockIdx.x * 256 + t;
    int v = (i < n) ? deg[i] : 0;
    buf[t] = v;
    __syncthreads();
    for (int off = 1; off < 256; off <<= 1) {
        int tmp = (t >= off) ? buf[t - off] : 0;
        __syncthreads();
        buf[t] += tmp;
        __syncthreads();
    }
    if (i < n) chunk[i] = buf[t];          // inclusive scan of chunk
    if (t == 255) bsum[blockIdx.x] = buf[255];
}

__global__ __launch_bounds__(128) void scan2_kernel(int* __restrict__ bsum, int nb) {
    __shared__ int buf[128];
    int t = threadIdx.x;
    int v = (t < nb) ? bsum[t] : 0;
    buf[t] = v;
    __syncthreads();
    for (int off = 1; off < 128; off <<= 1) {
        int tmp = (t >= off) ? buf[t - off] : 0;
        __syncthreads();
        buf[t] += tmp;
        __syncthreads();
    }
    if (t < nb) bsum[t] = buf[t] - v;      // exclusive
}

__global__ __launch_bounds__(256) void scan3_kernel(const int* __restrict__ chunk,
                                                    const int* __restrict__ bsum,
                                                    int* __restrict__ offs, int n) {
    int i = blockIdx.x * 256 + threadIdx.x;
    if (i < n) offs[i + 1] = chunk[i] + bsum[i >> 8];
    if (i == 0) offs[0] = 0;
}

__global__ __launch_bounds__(256) void scatter_kernel(const int* __restrict__ src,
                                                      const int* __restrict__ dst,
                                                      const int* __restrict__ offs,
                                                      int* __restrict__ cursor,
                                                      int* __restrict__ csr_src, int e) {
    int i = blockIdx.x * blockDim.x + threadIdx.x;
    if (i < e) {
        int d = dst[i];
        int pos = offs[d] + atomicAdd(&cursor[d], 1);
        csr_src[pos] = src[i];
    }
}

// ---------------- weight prep: build transposed split-bf16 W_cat ----------------
// id-ordered dst rows: [0,1536): layers0-2 (li*512+n: q|k|v|s) ; [1536,1664): Wp ;
// [1664,1792): Ws3 ; [1792,4864): layer3 (h*384+j: q|k|v per head)
__global__ __launch_bounds__(128) void prep_w_kernel(
    const float* __restrict__ Wq, const float* __restrict__ Wk,
    const float* __restrict__ Wv, const float* __restrict__ Ws,
    const float* __restrict__ Wp, const float* __restrict__ Ws3,
    const float* __restrict__ Wq3, const float* __restrict__ Wk3,
    const float* __restrict__ Wv3, unsigned short* __restrict__ WtAll) {
    int id = blockIdx.x;
    int k = threadIdx.x;  // 0..127 (original K index)
    float w;
    if (id < 1536) {
        int li = id / 512, n = id % 512, sel = n >> 7, np = n & 127;
        const float* W = (sel == 0) ? Wq : (sel == 1) ? Wk : (sel == 2) ? Wv : Ws;
        w = W[li * 16384 + k * 128 + np];
    } else if (id < 1664) {
        int n = id - 1536;
        w = Wp[k * 128 + n];
    } else if (id < 1792) {
        int n = id - 1664;
        w = Ws3[k * 128 + n];
    } else {
        int r = id - 1792, h = r / 384, j = r % 384, sel = j >> 7, jp = j & 127;
        const float* W = (sel == 0) ? Wq3 : (sel == 1) ? Wk3 : Wv3;
        w = W[k * 1024 + h * 128 + jp];
    }
    unsigned short hi = f2bf(w);
    unsigned short lo = f2bf(w - bf2f(hi));
    unsigned short* dst = WtAll + (size_t)id * KC;
    dst[k] = hi;
    dst[128 + k] = hi;
    dst[256 + k] = lo;
}

__global__ __launch_bounds__(256) void prep_bias_kernel(
    const float* __restrict__ bq, const float* __restrict__ bk,
    const float* __restrict__ bv, const float* __restrict__ bs,
    const float* __restrict__ bq3, const float* __restrict__ bk3,
    const float* __restrict__ bv3, float* __restrict__ bcat) {
    int id = blockIdx.x * 256 + threadIdx.x;
    if (id >= 4608) return;
    float v;
    if (id < 1536) {
        int li = id / 512, n = id % 512, sel = n >> 7, np = n & 127;
        const float* b = (sel == 0) ? bq : (sel == 1) ? bk : (sel == 2) ? bv : bs;
        v = b[li * 128 + np];
    } else {
        int r = id - 1536, h = r / 384, j = r % 384, sel = j >> 7, jp = j & 127;
        const float* b = (sel == 0) ? bq3 : (sel == 1) ? bk3 : bv3;
        v = b[h * 128 + jp];
    }
    bcat[id] = v;
}

// ---------------- activation -> split-bf16 A_cat (pads zero-filled) ----------------
__global__ __launch_bounds__(256) void cat_from_kernel(const float* __restrict__ h,
                                                       unsigned short* __restrict__ Acat) {
    int idx = blockIdx.x * 256 + threadIdx.x;
    if (idx >= NPAD * HIDDIM) return;
    int r = idx >> 7, k = idx & 127;
    float x = (r < NNODES) ? h[idx] : 0.f;
    unsigned short hi = f2bf(x);
    unsigned short lo = f2bf(x - bf2f(hi));
    unsigned short* row = Acat + (size_t)r * KC;
    row[k] = hi;
    row[128 + k] = lo;
    row[256 + k] = hi;
}

// ---------------- MFMA GEMM: C[nrows x M] = Acat @ Wt^T + bias ----------------
// Acat: [NPAD][KC] bf16 bits ; Wt: [M][KC] bf16 bits (row = output col)
// grid (NPAD/64, M/128), block 256 (4 waves); wave w: rows blk*64+w*16, 8 col tiles
__global__ __launch_bounds__(256) void gemm_mfma_kernel(
    const unsigned short* __restrict__ Acat, const unsigned short* __restrict__ Wt,
    const float* __restrict__ bias, float* __restrict__ C, int M, int nrows) {
    int lane = threadIdx.x & 63;
    int wave = threadIdx.x >> 6;
    int rowBase = blockIdx.x * 64 + wave * 16;
    int colBase = blockIdx.y * 128;
    int m = lane & 15;
    int ko = (lane >> 4) * 8;
    const unsigned short* aptr = Acat + (size_t)(rowBase + m) * KC + ko;
    const unsigned short* bptr = Wt + (size_t)(colBase + m) * KC + ko;
    floatx4 acc[8];
#pragma unroll
    for (int c = 0; c < 8; ++c) acc[c] = (floatx4){0.f, 0.f, 0.f, 0.f};
#pragma unroll 2
    for (int kg = 0; kg < 12; ++kg) {
        short8 a = *(const short8*)(aptr + kg * 32);
#pragma unroll
        for (int c = 0; c < 8; ++c) {
            short8 b = *(const short8*)(bptr + (size_t)c * 16 * KC + kg * 32);
            acc[c] = __builtin_amdgcn_mfma_f32_16x16x32_bf16(a, b, acc[c], 0, 0, 0);
        }
    }
    int r0 = rowBase + (lane >> 4) * 4;
#pragma unroll
    for (int c = 0; c < 8; ++c) {
        int col = colBase + c * 16 + m;
        float bv = bias[col];
#pragma unroll
        for (int j = 0; j < 4; ++j) {
            int row = r0 + j;
            if (row < nrows) C[(size_t)row * M + col] = acc[c][j] + bv;
        }
    }
}

// ---------------- attention layers 0-2 (8 heads x d=16) + beta gate ----------------
__global__ __launch_bounds__(128) void attn_small_kernel(
    const float* __restrict__ qkvs, const float* __restrict__ Wb,
    const int* __restrict__ offs, const int* __restrict__ csr_src,
    float* __restrict__ out) {
    int i = blockIdx.x;
    int t = threadIdx.x;  // head*16 + dim
    float qt = qkvs[(size_t)i * QS + t];
    int e0 = offs[i], e1 = offs[i + 1];
    float mm = -1e30f, l = 0.f, acc = 0.f;
    for (int e = e0; e < e1; ++e) {
        int sn = csr_src[e];
        const float* row = qkvs + (size_t)sn * QS;
        float kt = row[128 + t];
        float vt = row[256 + t];
        float p = qt * kt;
        p += __shfl_xor(p, 1);
        p += __shfl_xor(p, 2);
        p += __shfl_xor(p, 4);
        p += __shfl_xor(p, 8);
        float logit = p * 0.25f;  // 1/sqrt(16)
        float mnew = fmaxf(mm, logit);
        float sc = __expf(mm - mnew);
        float w = __expf(logit - mnew);
        acc = acc * sc + w * vt;
        l = l * sc + w;
        mm = mnew;
    }
    float o = acc / (l + 1e-16f);
    float r = qkvs[(size_t)i * QS + 384 + t];
    float part = o * Wb[t] + r * Wb[128 + t] + (o - r) * Wb[256 + t];
#pragma unroll
    for (int msk = 1; msk <= 32; msk <<= 1) part += __shfl_xor(part, msk);
    __shared__ float wsum[2];
    if ((t & 63) == 0) wsum[t >> 6] = part;
    __syncthreads();
    float tot = wsum[0] + wsum[1];
    float g = 1.f / (1.f + __expf(-tot));
    out[(size_t)i * HIDDIM + t] = g * r + (1.f - g) * o;
}

// ---------------- attention layer 3, one head (d=128), 1 wave/node ----------------
__global__ __launch_bounds__(64) void attn_big_kernel(
    const float* __restrict__ qkv3, const int* __restrict__ offs,
    const int* __restrict__ csr_src, float* __restrict__ outacc) {
    int i = blockIdx.x;
    int t = threadIdx.x;  // 0..63, dims 2t,2t+1
    float2 qv = *(const float2*)(qkv3 + (size_t)i * KC + 2 * t);
    int e0 = offs[i], e1 = offs[i + 1];
    float mm = -1e30f, l = 0.f;
    float ax = 0.f, ay = 0.f;
    for (int e = e0; e < e1; ++e) {
        int sn = csr_src[e];
        const float* row = qkv3 + (size_t)sn * KC;
        float2 kv = *(const float2*)(row + 128 + 2 * t);
        float2 vv = *(const float2*)(row + 256 + 2 * t);
        float p = qv.x * kv.x + qv.y * kv.y;
#pragma unroll
        for (int msk = 1; msk <= 32; msk <<= 1) p += __shfl_xor(p, msk);
        float logit = p * 0.08838834764831845f;  // 1/sqrt(128)
        float mnew = fmaxf(mm, logit);
        float sc = __expf(mm - mnew);
        float w = __expf(logit - mnew);
        ax = ax * sc + w * vv.x;
        ay = ay * sc + w * vv.y;
        l = l * sc + w;
        mm = mnew;
    }
    float inv = 1.f / (l + 1e-16f);
    float* o = outacc + (size_t)i * HIDDIM + 2 * t;
    o[0] += ax * inv;
    o[1] += ay * inv;
}

// ---------------- beta gate layer 3 ----------------
__global__ __launch_bounds__(128) void beta3_kernel(float* __restrict__ obuf,
                                                    const float* __restrict__ s,
                                                    const float* __restrict__ Wb) {
    int i = blockIdx.x, t = threadIdx.x;
    float o = obuf[(size_t)i * HIDDIM + t] * 0.125f;
    float r = s[(size_t)i * HIDDIM + t];
    float part = o * Wb[t] + r * Wb[128 + t] + (o - r) * Wb[256 + t];
#pragma unroll
    for (int msk = 1; msk <= 32; msk <<= 1) part += __shfl_xor(part, msk);
    __shared__ float wsum[2];
    if ((t & 63) == 0) wsum[t >> 6] = part;
    __syncthreads();
    float tot = wsum[0] + wsum[1];
    float g = 1.f / (1.f + __expf(-tot));
    obuf[(size_t)i * HIDDIM + t] = g * r + (1.f - g) * o;
}

// ---------------- batchnorm ----------------
__global__ __launch_bounds__(128) void bn_stats_kernel(const float* __restrict__ x,
                                                       float* __restrict__ stat, int n) {
    int t = threadIdx.x;
    float s = 0.f, sq = 0.f;
    for (int i = blockIdx.x; i < n; i += gridDim.x) {
        float v = x[(size_t)i * HIDDIM + t];
        s += v;
        sq += v * v;
    }
    atomicAdd(&stat[t], s);
    atomicAdd(&stat[HIDDIM + t], sq);
}

// apply + relu, optionally emit split-bf16 A_cat for the next layer's GEMM
__global__ __launch_bounds__(128) void bn_apply_kernel(float* __restrict__ x,
                                                       const float* __restrict__ stat,
                                                       const float* __restrict__ gamma,
                                                       const float* __restrict__ beta, int n,
                                                       unsigned short* __restrict__ cat) {
    int t = threadIdx.x;
    float mu = stat[t] / (float)n;
    float var = stat[HIDDIM + t] / (float)n - mu * mu;
    float rs = rsqrtf(var + 1e-5f);
    float g = gamma[t], b = beta[t];
    for (int i = blockIdx.x; i < n; i += gridDim.x) {
        float v = x[(size_t)i * HIDDIM + t];
        v = fmaxf((v - mu) * rs * g + b, 0.f);
        x[(size_t)i * HIDDIM + t] = v;
        if (cat) {
            unsigned short hi = f2bf(v);
            unsigned short lo = f2bf(v - bf2f(hi));
            unsigned short* row = cat + (size_t)i * KC;
            row[t] = hi;
            row[128 + t] = lo;
            row[256 + t] = hi;
        }
    }
}

// ---------------- pool via sorted-batch ranges ----------------
__global__ __launch_bounds__(256) void gb_kernel(const int* __restrict__ batch,
                                                 int* __restrict__ gs,
                                                 int* __restrict__ ge, int n) {
    int i = blockIdx.x * 256 + threadIdx.x;
    if (i >= n) return;
    int b = batch[i];
    if (i == 0 || batch[i - 1] != b) gs[b] = i;
    if (i == n - 1 || batch[i + 1] != b) ge[b] = i + 1;
}

__global__ __launch_bounds__(256) void pool_kernel(const float* __restrict__ x,
                                                   const int* __restrict__ gs,
                                                   const int* __restrict__ ge,
                                                   float* __restrict__ out) {
    int g = blockIdx.x;
    int t = threadIdx.x;
    int f = t & 127, half = t >> 7;
    int s = gs[g], e = ge[g];
    float acc = 0.f;
    for (int i = s + half; i < e; i += 2) acc += x[(size_t)i * HIDDIM + f];
    __shared__ float l0[128];
    if (half == 0) l0[f] = acc;
    __syncthreads();
    if (half == 1) {
        float tot = l0[f] + acc;
        int c = e - s;
        out[g * HIDDIM + f] = tot / (float)(c > 0 ? c : 1);
    }
}

// ---------------- host ----------------
extern "C" void kernel_launch(void* const* d_in, const int* in_sizes, int n_in,
                              void* d_out, int out_size, void* d_ws, size_t ws_size,
                              hipStream_t stream) {
    const float* x       = (const float*)d_in[0];
    const int*   ei      = (const int*)d_in[1];
    const int*   batch   = (const int*)d_in[2];
    const float* Wp      = (const float*)d_in[3];
    const float* bp      = (const float*)d_in[4];
    const float* Wq      = (const float*)d_in[5];
    const float* bq      = (const float*)d_in[6];
    const float* Wk      = (const float*)d_in[7];
    const float* bk      = (const float*)d_in[8];
    const float* Wv      = (const float*)d_in[9];
    const float* bv      = (const float*)d_in[10];
    const float* Ws      = (const float*)d_in[11];
    const float* bs      = (const float*)d_in[12];
    const float* Wbeta   = (const float*)d_in[13];
    const float* Wq3     = (const float*)d_in[14];
    const float* bq3     = (const float*)d_in[15];
    const float* Wk3     = (const float*)d_in[16];
    const float* bk3     = (const float*)d_in[17];
    const float* Wv3     = (const float*)d_in[18];
    const float* bv3     = (const float*)d_in[19];
    const float* Ws3     = (const float*)d_in[20];
    const float* bs3     = (const float*)d_in[21];
    const float* Wbeta3  = (const float*)d_in[22];
    const float* bn_gamma = (const float*)d_in[23];
    const float* bn_beta  = (const float*)d_in[24];
    float* out = (float*)d_out;

    const int* esrc = ei;
    const int* edst = ei + NEDGES;

    char* wpc = (char*)d_ws;
    auto alloc = [&](size_t nbytes) -> char* {
        char* p = wpc;
        wpc += (nbytes + 255) & ~(size_t)255;
        return p;
    };
    unsigned short* Acat  = (unsigned short*)alloc((size_t)NPAD * KC * 2);
    unsigned short* WtAll = (unsigned short*)alloc((size_t)4864 * KC * 2);
    float* bcat  = (float*)alloc(4608 * 4);
    float* qkvs  = (float*)alloc((size_t)NNODES * QS * 4);   // also aliases qkv3 (N x 384)
    float* hbuf  = (float*)alloc((size_t)NNODES * HIDDIM * 4);
    float* obuf  = (float*)alloc((size_t)NNODES * HIDDIM * 4);
    float* sb    = (float*)alloc((size_t)NNODES * HIDDIM * 4);
    // contiguous zero region: deg | cursor | gs | ge | bnstat4
    int*   deg    = (int*)alloc((2 * NNODES + 128 + 4 * 256) * 4);
    int*   cursor = deg + NNODES;
    int*   gs     = deg + 2 * NNODES;
    int*   ge     = gs + NGRAPH;
    float* bnstat4 = (float*)(deg + 2 * NNODES + 128);
    int*   chunk  = (int*)alloc(NNODES * 4);
    int*   bsum   = (int*)alloc(128 * 4);
    int*   offs   = (int*)alloc((NNODES + 1) * 4);
    int*   csrsrc = (int*)alloc(NEDGES * 4);

    unsigned short* WtL  = WtAll;                    // [3][512][KC]
    unsigned short* Wpt  = WtAll + (size_t)1536 * KC;
    unsigned short* Ws3t = WtAll + (size_t)1664 * KC;
    unsigned short* Wt3  = WtAll + (size_t)1792 * KC; // [8][384][KC]
    float* bcatL = bcat;          // [3][512]
    float* b3cat = bcat + 1536;   // [8][384]
    float* qkv3 = qkvs;           // alias

    const int TB = 256;
    const int ZWORDS = 2 * NNODES + 128 + 4 * 256;
    // ---- zero scratch counters/stats ----
    zero_kernel<<<(ZWORDS + TB - 1) / TB, TB, 0, stream>>>((float*)deg, ZWORDS);
    // ---- CSR build ----
    count_deg_kernel<<<(NEDGES + TB - 1) / TB, TB, 0, stream>>>(edst, deg, NEDGES);
    const int NB = (NNODES + 255) / 256;  // 79
    scan1_kernel<<<NB, 256, 0, stream>>>(deg, chunk, bsum, NNODES);
    scan2_kernel<<<1, 128, 0, stream>>>(bsum, NB);
    scan3_kernel<<<NB, 256, 0, stream>>>(chunk, bsum, offs, NNODES);
    scatter_kernel<<<(NEDGES + TB - 1) / TB, TB, 0, stream>>>(esrc, edst, offs, cursor, csrsrc, NEDGES);
    gb_kernel<<<(NNODES + TB - 1) / TB, TB, 0, stream>>>(batch, gs, ge, NNODES);

    // ---- weight/bias prep ----
    prep_w_kernel<<<4864, 128, 0, stream>>>(Wq, Wk, Wv, Ws, Wp, Ws3, Wq3, Wk3, Wv3, WtAll);
    prep_bias_kernel<<<(4608 + TB - 1) / TB, TB, 0, stream>>>(bq, bk, bv, bs, bq3, bk3, bv3, bcat);

    const int CATB = (NPAD * HIDDIM + TB - 1) / TB;
    dim3 g512((NPAD / 64), 4), g384((NPAD / 64), 3), g128((NPAD / 64), 1);

    // ---- initial projection ----
    cat_from_kernel<<<CATB, TB, 0, stream>>>(x, Acat);
    gemm_mfma_kernel<<<g128, 256, 0, stream>>>(Acat, Wpt, bp, hbuf, 128, NNODES);
    cat_from_kernel<<<CATB, TB, 0, stream>>>(hbuf, Acat);

    // ---- layers 0..2 ----
    for (int li = 0; li < 3; ++li) {
        gemm_mfma_kernel<<<g512, 256, 0, stream>>>(Acat, WtL + (size_t)li * 512 * KC,
                                                   bcatL + li * 512, qkvs, 512, NNODES);
        attn_small_kernel<<<NNODES, 128, 0, stream>>>(qkvs, Wbeta + li * 384, offs, csrsrc, obuf);
        float* st = bnstat4 + li * 256;
        bn_stats_kernel<<<200, 128, 0, stream>>>(obuf, st, NNODES);
        bn_apply_kernel<<<256, 128, 0, stream>>>(obuf, st, bn_gamma + li * HIDDIM,
                                                 bn_beta + li * HIDDIM, NNODES, Acat);
    }

    // ---- layer 3 ----
    zero_kernel<<<(NNODES * HIDDIM + TB - 1) / TB, TB, 0, stream>>>(hbuf, NNODES * HIDDIM);
    for (int hd = 0; hd < NHEADS; ++hd) {
        gemm_mfma_kernel<<<g384, 256, 0, stream>>>(Acat, Wt3 + (size_t)hd * 384 * KC,
                                                   b3cat + hd * 384, qkv3, 384, NNODES);
        attn_big_kernel<<<NNODES, 64, 0, stream>>>(qkv3, offs, csrsrc, hbuf);
    }
    gemm_mfma_kernel<<<g128, 256, 0, stream>>>(Acat, Ws3t, bs3, sb, 128, NNODES);
    beta3_kernel<<<NNODES, 128, 0, stream>>>(hbuf, sb, Wbeta3);
    float* st3 = bnstat4 + 3 * 256;
    bn_stats_kernel<<<200, 128, 0, stream>>>(hbuf, st3, NNODES);
    bn_apply_kernel<<<256, 128, 0, stream>>>(hbuf, st3, bn_gamma + 3 * HIDDIM,
                                             bn_beta + 3 * HIDDIM, NNODES, (unsigned short*)0);

    // ---- global mean pool ----
    pool_kernel<<<NGRAPH, 256, 0, stream>>>(hbuf, gs, ge, out);
}

// Round 3
// 1325.856 us; speedup vs baseline: 1.9869x; 1.0736x over previous
//
#include <hip/hip_runtime.h>
#include <math.h>

#define NNODES 20000
#define NPAD   20096   // 157 * 128
#define NEDGES 160000
#define HIDDIM 128
#define NHEADS 8
#define NGRAPH 64
#define KC 384   // concatenated K (hi | lo | hi)

typedef short short8 __attribute__((ext_vector_type(8)));
typedef float floatx4 __attribute__((ext_vector_type(4)));

__device__ inline unsigned short f2bf(float x) {
    unsigned u = __float_as_uint(x);
    u += 0x7fff + ((u >> 16) & 1);   // round-to-nearest-even
    return (unsigned short)(u >> 16);
}
__device__ inline float bf2f(unsigned short h) {
    return __uint_as_float(((unsigned)h) << 16);
}

// ---------------- utility ----------------
__global__ __launch_bounds__(256) void zero_kernel(float* __restrict__ p, int n) {
    int i = blockIdx.x * blockDim.x + threadIdx.x;
    if (i < n) p[i] = 0.f;
}

// ---------------- CSR build ----------------
__global__ __launch_bounds__(256) void count_deg_kernel(const int* __restrict__ dst,
                                                        int* __restrict__ deg, int e) {
    int i = blockIdx.x * blockDim.x + threadIdx.x;
    if (i < e) atomicAdd(&deg[dst[i]], 1);
}

__global__ __launch_bounds__(256) void scan1_kernel(const int* __restrict__ deg,
                                                    int* __restrict__ chunk,
                                                    int* __restrict__ bsum, int n) {
    __shared__ int buf[256];
    int t = threadIdx.x;
    int i = blockIdx.x * 256 + t;
    int v = (i < n) ? deg[i] : 0;
    buf[t] = v;
    __syncthreads();
    for (int off = 1; off < 256; off <<= 1) {
        int tmp = (t >= off) ? buf[t - off] : 0;
        __syncthreads();
        buf[t] += tmp;
        __syncthreads();
    }
    if (i < n) chunk[i] = buf[t];
    if (t == 255) bsum[blockIdx.x] = buf[255];
}

__global__ __launch_bounds__(128) void scan2_kernel(int* __restrict__ bsum, int nb) {
    __shared__ int buf[128];
    int t = threadIdx.x;
    int v = (t < nb) ? bsum[t] : 0;
    buf[t] = v;
    __syncthreads();
    for (int off = 1; off < 128; off <<= 1) {
        int tmp = (t >= off) ? buf[t - off] : 0;
        __syncthreads();
        buf[t] += tmp;
        __syncthreads();
    }
    if (t < nb) bsum[t] = buf[t] - v;
}

__global__ __launch_bounds__(256) void scan3_kernel(const int* __restrict__ chunk,
                                                    const int* __restrict__ bsum,
                                                    int* __restrict__ offs, int n) {
    int i = blockIdx.x * 256 + threadIdx.x;
    if (i < n) offs[i + 1] = chunk[i] + bsum[i >> 8];
    if (i == 0) offs[0] = 0;
}

__global__ __launch_bounds__(256) void scatter_kernel(const int* __restrict__ src,
                                                      const int* __restrict__ dst,
                                                      const int* __restrict__ offs,
                                                      int* __restrict__ cursor,
                                                      int* __restrict__ csr_src, int e) {
    int i = blockIdx.x * blockDim.x + threadIdx.x;
    if (i < e) {
        int d = dst[i];
        int pos = offs[d] + atomicAdd(&cursor[d], 1);
        csr_src[pos] = src[i];
    }
}

// ---------------- weight prep: transposed split-bf16 rows ----------------
// [0,1536): layers0-2, per layer 512 rows ordered q|s|k|v ; [1536,1664): Wp ;
// [1664,1792): Ws3 ; [1792,4864): layer3, per head 384 rows q|k|v
__global__ __launch_bounds__(128) void prep_w_kernel(
    const float* __restrict__ Wq, const float* __restrict__ Wk,
    const float* __restrict__ Wv, const float* __restrict__ Ws,
    const float* __restrict__ Wp, const float* __restrict__ Ws3,
    const float* __restrict__ Wq3, const float* __restrict__ Wk3,
    const float* __restrict__ Wv3, unsigned short* __restrict__ WtAll) {
    int id = blockIdx.x;
    int k = threadIdx.x;  // original K index
    float w;
    if (id < 1536) {
        int li = id / 512, n = id % 512, sel = n >> 7, np = n & 127;
        const float* W = (sel == 0) ? Wq : (sel == 1) ? Ws : (sel == 2) ? Wk : Wv;
        w = W[li * 16384 + k * 128 + np];
    } else if (id < 1664) {
        int n = id - 1536;
        w = Wp[k * 128 + n];
    } else if (id < 1792) {
        int n = id - 1664;
        w = Ws3[k * 128 + n];
    } else {
        int r = id - 1792, h = r / 384, j = r % 384, sel = j >> 7, jp = j & 127;
        const float* W = (sel == 0) ? Wq3 : (sel == 1) ? Wk3 : Wv3;
        w = W[k * 1024 + h * 128 + jp];
    }
    unsigned short hi = f2bf(w);
    unsigned short lo = f2bf(w - bf2f(hi));
    unsigned short* dst = WtAll + (size_t)id * KC;
    dst[k] = hi;
    dst[128 + k] = hi;
    dst[256 + k] = lo;
}

__global__ __launch_bounds__(256) void prep_bias_kernel(
    const float* __restrict__ bq, const float* __restrict__ bk,
    const float* __restrict__ bv, const float* __restrict__ bs,
    const float* __restrict__ bq3, const float* __restrict__ bk3,
    const float* __restrict__ bv3, float* __restrict__ bcat) {
    int id = blockIdx.x * 256 + threadIdx.x;
    if (id >= 4608) return;
    float v;
    if (id < 1536) {
        int li = id / 512, n = id % 512, sel = n >> 7, np = n & 127;
        const float* b = (sel == 0) ? bq : (sel == 1) ? bs : (sel == 2) ? bk : bv;
        v = b[li * 128 + np];
    } else {
        int r = id - 1536, h = r / 384, j = r % 384, sel = j >> 7, jp = j & 127;
        const float* b = (sel == 0) ? bq3 : (sel == 1) ? bk3 : bv3;
        v = b[h * 128 + jp];
    }
    bcat[id] = v;
}

// ---------------- activation -> split-bf16 A_cat (pads zero-filled) ----------------
__global__ __launch_bounds__(256) void cat_from_kernel(const float* __restrict__ h,
                                                       unsigned short* __restrict__ Acat) {
    int idx = blockIdx.x * 256 + threadIdx.x;
    if (idx >= NPAD * HIDDIM) return;
    int r = idx >> 7, k = idx & 127;
    float x = (r < NNODES) ? h[idx] : 0.f;
    unsigned short hi = f2bf(x);
    unsigned short lo = f2bf(x - bf2f(hi));
    unsigned short* row = Acat + (size_t)r * KC;
    row[k] = hi;
    row[128 + k] = lo;
    row[256 + k] = hi;
}

// ---------------- MFMA GEMM ----------------
// Acat: [NPAD][KC] ; Wt: [M][KC] (row = output col). grid (NPAD/128, M/128),
// block 256 = 4 waves; wave w -> rows (w&1)*64, cols (w>>1)*64 within the tile;
// each wave computes a 64x64 patch as 4x4 MFMA 16x16x32 tiles.
template <typename OutT>
__global__ __launch_bounds__(256) void gemm_mfma_kernel(
    const unsigned short* __restrict__ Acat, const unsigned short* __restrict__ Wt,
    const float* __restrict__ bias, OutT* __restrict__ C, int M, int nrows) {
    int lane = threadIdx.x & 63;
    int wave = threadIdx.x >> 6;
    int rowBase = blockIdx.x * 128 + (wave & 1) * 64;
    int colBase = blockIdx.y * 128 + (wave >> 1) * 64;
    int m = lane & 15;
    int ko = (lane >> 4) * 8;
    const unsigned short* aptr = Acat + (size_t)(rowBase + m) * KC + ko;
    const unsigned short* bptr = Wt + (size_t)(colBase + m) * KC + ko;
    floatx4 acc[4][4];
#pragma unroll
    for (int r = 0; r < 4; ++r)
#pragma unroll
        for (int c = 0; c < 4; ++c) acc[r][c] = (floatx4){0.f, 0.f, 0.f, 0.f};
#pragma unroll
    for (int kg = 0; kg < 12; ++kg) {
        short8 a[4], b[4];
#pragma unroll
        for (int r = 0; r < 4; ++r) a[r] = *(const short8*)(aptr + (size_t)r * 16 * KC + kg * 32);
#pragma unroll
        for (int c = 0; c < 4; ++c) b[c] = *(const short8*)(bptr + (size_t)c * 16 * KC + kg * 32);
#pragma unroll
        for (int r = 0; r < 4; ++r)
#pragma unroll
            for (int c = 0; c < 4; ++c)
                acc[r][c] = __builtin_amdgcn_mfma_f32_16x16x32_bf16(a[r], b[c], acc[r][c], 0, 0, 0);
    }
    int r0 = rowBase + (lane >> 4) * 4;
#pragma unroll
    for (int c = 0; c < 4; ++c) {
        int col = colBase + c * 16 + m;
        float bv = bias[col];
#pragma unroll
        for (int r = 0; r < 4; ++r) {
#pragma unroll
            for (int j = 0; j < 4; ++j) {
                int row = r0 + r * 16 + j;
                if (row < nrows) {
                    float val = acc[r][c][j] + bv;
                    if (sizeof(OutT) == 2)
                        ((unsigned short*)C)[(size_t)row * M + col] = f2bf(val);
                    else
                        ((float*)C)[(size_t)row * M + col] = val;
                }
            }
        }
    }
}

// ---------------- attention layers 0-2 (8 heads x d=16) + beta gate ----------------
// qs: [N][256] fp32 (q|s) ; kv: [N][256] bf16 (k|v)
__global__ __launch_bounds__(128) void attn_small_kernel(
    const float* __restrict__ qs, const unsigned short* __restrict__ kv,
    const float* __restrict__ Wb,
    const int* __restrict__ offs, const int* __restrict__ csr_src,
    float* __restrict__ out) {
    int i = blockIdx.x;
    int t = threadIdx.x;  // head*16 + dim
    float qt = qs[(size_t)i * 256 + t];
    int e0 = offs[i], e1 = offs[i + 1];
    float mm = -1e30f, l = 0.f, acc = 0.f;
    for (int e = e0; e < e1; ++e) {
        int sn = csr_src[e];
        const unsigned short* row = kv + (size_t)sn * 256;
        float kt = bf2f(row[t]);
        float vt = bf2f(row[128 + t]);
        float p = qt * kt;
        p += __shfl_xor(p, 1);
        p += __shfl_xor(p, 2);
        p += __shfl_xor(p, 4);
        p += __shfl_xor(p, 8);
        float logit = p * 0.25f;  // 1/sqrt(16)
        float mnew = fmaxf(mm, logit);
        float sc = __expf(mm - mnew);
        float w = __expf(logit - mnew);
        acc = acc * sc + w * vt;
        l = l * sc + w;
        mm = mnew;
    }
    float o = acc / (l + 1e-16f);
    float r = qs[(size_t)i * 256 + 128 + t];
    float part = o * Wb[t] + r * Wb[128 + t] + (o - r) * Wb[256 + t];
#pragma unroll
    for (int msk = 1; msk <= 32; msk <<= 1) part += __shfl_xor(part, msk);
    __shared__ float wsum[2];
    if ((t & 63) == 0) wsum[t >> 6] = part;
    __syncthreads();
    float tot = wsum[0] + wsum[1];
    float g = 1.f / (1.f + __expf(-tot));
    out[(size_t)i * HIDDIM + t] = g * r + (1.f - g) * o;
}

// ---------------- attention layer 3, one head (d=128), 1 wave/node ----------------
// qb: [N][128] fp32 ; kv: [N][256] bf16 (k|v)
__global__ __launch_bounds__(64) void attn_big_kernel(
    const float* __restrict__ qb, const unsigned short* __restrict__ kv,
    const int* __restrict__ offs, const int* __restrict__ csr_src,
    float* __restrict__ outacc) {
    int i = blockIdx.x;
    int t = threadIdx.x;  // dims 2t, 2t+1
    float2 qv = *(const float2*)(qb + (size_t)i * HIDDIM + 2 * t);
    int e0 = offs[i], e1 = offs[i + 1];
    float mm = -1e30f, l = 0.f;
    float ax = 0.f, ay = 0.f;
    for (int e = e0; e < e1; ++e) {
        int sn = csr_src[e];
        const unsigned short* row = kv + (size_t)sn * 256;
        unsigned kk = *(const unsigned*)(row + 2 * t);
        unsigned vv = *(const unsigned*)(row + 128 + 2 * t);
        float kx = bf2f((unsigned short)(kk & 0xffff));
        float ky = bf2f((unsigned short)(kk >> 16));
        float vx = bf2f((unsigned short)(vv & 0xffff));
        float vy = bf2f((unsigned short)(vv >> 16));
        float p = qv.x * kx + qv.y * ky;
#pragma unroll
        for (int msk = 1; msk <= 32; msk <<= 1) p += __shfl_xor(p, msk);
        float logit = p * 0.08838834764831845f;  // 1/sqrt(128)
        float mnew = fmaxf(mm, logit);
        float sc = __expf(mm - mnew);
        float w = __expf(logit - mnew);
        ax = ax * sc + w * vx;
        ay = ay * sc + w * vy;
        l = l * sc + w;
        mm = mnew;
    }
    float inv = 1.f / (l + 1e-16f);
    float* o = outacc + (size_t)i * HIDDIM + 2 * t;
    o[0] += ax * inv;
    o[1] += ay * inv;
}

// ---------------- beta gate layer 3 ----------------
__global__ __launch_bounds__(128) void beta3_kernel(float* __restrict__ obuf,
                                                    const float* __restrict__ s,
                                                    const float* __restrict__ Wb) {
    int i = blockIdx.x, t = threadIdx.x;
    float o = obuf[(size_t)i * HIDDIM + t] * 0.125f;
    float r = s[(size_t)i * HIDDIM + t];
    float part = o * Wb[t] + r * Wb[128 + t] + (o - r) * Wb[256 + t];
#pragma unroll
    for (int msk = 1; msk <= 32; msk <<= 1) part += __shfl_xor(part, msk);
    __shared__ float wsum[2];
    if ((t & 63) == 0) wsum[t >> 6] = part;
    __syncthreads();
    float tot = wsum[0] + wsum[1];
    float g = 1.f / (1.f + __expf(-tot));
    obuf[(size_t)i * HIDDIM + t] = g * r + (1.f - g) * o;
}

// ---------------- batchnorm ----------------
__global__ __launch_bounds__(128) void bn_stats_kernel(const float* __restrict__ x,
                                                       float* __restrict__ stat, int n) {
    int t = threadIdx.x;
    float s = 0.f, sq = 0.f;
    for (int i = blockIdx.x; i < n; i += gridDim.x) {
        float v = x[(size_t)i * HIDDIM + t];
        s += v;
        sq += v * v;
    }
    atomicAdd(&stat[t], s);
    atomicAdd(&stat[HIDDIM + t], sq);
}

__global__ __launch_bounds__(128) void bn_apply_kernel(float* __restrict__ x,
                                                       const float* __restrict__ stat,
                                                       const float* __restrict__ gamma,
                                                       const float* __restrict__ beta, int n,
                                                       unsigned short* __restrict__ cat) {
    int t = threadIdx.x;
    float mu = stat[t] / (float)n;
    float var = stat[HIDDIM + t] / (float)n - mu * mu;
    float rs = rsqrtf(var + 1e-5f);
    float g = gamma[t], b = beta[t];
    for (int i = blockIdx.x; i < n; i += gridDim.x) {
        float v = x[(size_t)i * HIDDIM + t];
        v = fmaxf((v - mu) * rs * g + b, 0.f);
        x[(size_t)i * HIDDIM + t] = v;
        if (cat) {
            unsigned short hi = f2bf(v);
            unsigned short lo = f2bf(v - bf2f(hi));
            unsigned short* row = cat + (size_t)i * KC;
            row[t] = hi;
            row[128 + t] = lo;
            row[256 + t] = hi;
        }
    }
}

// ---------------- pool via sorted-batch ranges ----------------
__global__ __launch_bounds__(256) void gb_kernel(const int* __restrict__ batch,
                                                 int* __restrict__ gs,
                                                 int* __restrict__ ge, int n) {
    int i = blockIdx.x * 256 + threadIdx.x;
    if (i >= n) return;
    int b = batch[i];
    if (i == 0 || batch[i - 1] != b) gs[b] = i;
    if (i == n - 1 || batch[i + 1] != b) ge[b] = i + 1;
}

__global__ __launch_bounds__(256) void pool_kernel(const float* __restrict__ x,
                                                   const int* __restrict__ gs,
                                                   const int* __restrict__ ge,
                                                   float* __restrict__ out) {
    int g = blockIdx.x;
    int t = threadIdx.x;
    int f = t & 127, half = t >> 7;
    int s = gs[g], e = ge[g];
    float acc = 0.f;
    for (int i = s + half; i < e; i += 2) acc += x[(size_t)i * HIDDIM + f];
    __shared__ float l0[128];
    if (half == 0) l0[f] = acc;
    __syncthreads();
    if (half == 1) {
        float tot = l0[f] + acc;
        int c = e - s;
        out[g * HIDDIM + f] = tot / (float)(c > 0 ? c : 1);
    }
}

// ---------------- host ----------------
extern "C" void kernel_launch(void* const* d_in, const int* in_sizes, int n_in,
                              void* d_out, int out_size, void* d_ws, size_t ws_size,
                              hipStream_t stream) {
    const float* x       = (const float*)d_in[0];
    const int*   ei      = (const int*)d_in[1];
    const int*   batch   = (const int*)d_in[2];
    const float* Wp      = (const float*)d_in[3];
    const float* bp      = (const float*)d_in[4];
    const float* Wq      = (const float*)d_in[5];
    const float* bq      = (const float*)d_in[6];
    const float* Wk      = (const float*)d_in[7];
    const float* bk      = (const float*)d_in[8];
    const float* Wv      = (const float*)d_in[9];
    const float* bv      = (const float*)d_in[10];
    const float* Ws      = (const float*)d_in[11];
    const float* bs      = (const float*)d_in[12];
    const float* Wbeta   = (const float*)d_in[13];
    const float* Wq3     = (const float*)d_in[14];
    const float* bq3     = (const float*)d_in[15];
    const float* Wk3     = (const float*)d_in[16];
    const float* bk3     = (const float*)d_in[17];
    const float* Wv3     = (const float*)d_in[18];
    const float* bv3     = (const float*)d_in[19];
    const float* Ws3     = (const float*)d_in[20];
    const float* bs3     = (const float*)d_in[21];
    const float* Wbeta3  = (const float*)d_in[22];
    const float* bn_gamma = (const float*)d_in[23];
    const float* bn_beta  = (const float*)d_in[24];
    float* out = (float*)d_out;

    const int* esrc = ei;
    const int* edst = ei + NEDGES;

    char* wpc = (char*)d_ws;
    auto alloc = [&](size_t nbytes) -> char* {
        char* p = wpc;
        wpc += (nbytes + 255) & ~(size_t)255;
        return p;
    };
    unsigned short* Acat  = (unsigned short*)alloc((size_t)NPAD * KC * 2);
    unsigned short* WtAll = (unsigned short*)alloc((size_t)4864 * KC * 2);
    float* bcat   = (float*)alloc(4608 * 4);
    float* qsbuf  = (float*)alloc((size_t)NNODES * 256 * 4);          // q|s fp32 (layer3: qb aliases)
    unsigned short* kvbuf = (unsigned short*)alloc((size_t)NNODES * 256 * 2);  // k|v bf16
    float* hbuf   = (float*)alloc((size_t)NNODES * HIDDIM * 4);
    float* obuf   = (float*)alloc((size_t)NNODES * HIDDIM * 4);
    float* sb     = (float*)alloc((size_t)NNODES * HIDDIM * 4);
    // contiguous zero region: deg | cursor | gs | ge | bnstat4
    int*   deg    = (int*)alloc((2 * NNODES + 128 + 4 * 256) * 4);
    int*   cursor = deg + NNODES;
    int*   gs     = deg + 2 * NNODES;
    int*   ge     = gs + NGRAPH;
    float* bnstat4 = (float*)(deg + 2 * NNODES + 128);
    int*   chunk  = (int*)alloc(NNODES * 4);
    int*   bsum   = (int*)alloc(128 * 4);
    int*   offs   = (int*)alloc((NNODES + 1) * 4);
    int*   csrsrc = (int*)alloc(NEDGES * 4);

    unsigned short* WtL  = WtAll;                      // [3][512][KC] rows q|s|k|v
    unsigned short* Wpt  = WtAll + (size_t)1536 * KC;
    unsigned short* Ws3t = WtAll + (size_t)1664 * KC;
    unsigned short* Wt3  = WtAll + (size_t)1792 * KC;  // [8][384][KC] rows q|k|v
    float* bcatL = bcat;
    float* b3cat = bcat + 1536;
    float* qb = qsbuf;  // layer-3 per-head q (fp32, [N][128]) aliases qs buffer

    const int TB = 256;
    const int ZWORDS = 2 * NNODES + 128 + 4 * 256;
    zero_kernel<<<(ZWORDS + TB - 1) / TB, TB, 0, stream>>>((float*)deg, ZWORDS);
    // ---- CSR build ----
    count_deg_kernel<<<(NEDGES + TB - 1) / TB, TB, 0, stream>>>(edst, deg, NEDGES);
    const int NB = (NNODES + 255) / 256;  // 79
    scan1_kernel<<<NB, 256, 0, stream>>>(deg, chunk, bsum, NNODES);
    scan2_kernel<<<1, 128, 0, stream>>>(bsum, NB);
    scan3_kernel<<<NB, 256, 0, stream>>>(chunk, bsum, offs, NNODES);
    scatter_kernel<<<(NEDGES + TB - 1) / TB, TB, 0, stream>>>(esrc, edst, offs, cursor, csrsrc, NEDGES);
    gb_kernel<<<(NNODES + TB - 1) / TB, TB, 0, stream>>>(batch, gs, ge, NNODES);

    // ---- weight/bias prep ----
    prep_w_kernel<<<4864, 128, 0, stream>>>(Wq, Wk, Wv, Ws, Wp, Ws3, Wq3, Wk3, Wv3, WtAll);
    prep_bias_kernel<<<(4608 + TB - 1) / TB, TB, 0, stream>>>(bq, bk, bv, bs, bq3, bk3, bv3, bcat);

    const int CATB = (NPAD * HIDDIM + TB - 1) / TB;
    const int GX = NPAD / 128;  // 157
    dim3 g1(GX, 1), g2(GX, 2);

    // ---- initial projection ----
    cat_from_kernel<<<CATB, TB, 0, stream>>>(x, Acat);
    gemm_mfma_kernel<float><<<g1, 256, 0, stream>>>(Acat, Wpt, bp, hbuf, 128, NNODES);
    cat_from_kernel<<<CATB, TB, 0, stream>>>(hbuf, Acat);

    // ---- layers 0..2 ----
    for (int li = 0; li < 3; ++li) {
        const unsigned short* Wl = WtL + (size_t)li * 512 * KC;
        gemm_mfma_kernel<float><<<g2, 256, 0, stream>>>(Acat, Wl, bcatL + li * 512,
                                                        qsbuf, 256, NNODES);
        gemm_mfma_kernel<unsigned short><<<g2, 256, 0, stream>>>(
            Acat, Wl + (size_t)256 * KC, bcatL + li * 512 + 256, kvbuf, 256, NNODES);
        attn_small_kernel<<<NNODES, 128, 0, stream>>>(qsbuf, kvbuf, Wbeta + li * 384,
                                                      offs, csrsrc, obuf);
        float* st = bnstat4 + li * 256;
        bn_stats_kernel<<<200, 128, 0, stream>>>(obuf, st, NNODES);
        bn_apply_kernel<<<256, 128, 0, stream>>>(obuf, st, bn_gamma + li * HIDDIM,
                                                 bn_beta + li * HIDDIM, NNODES, Acat);
    }

    // ---- layer 3 ----
    zero_kernel<<<(NNODES * HIDDIM + TB - 1) / TB, TB, 0, stream>>>(hbuf, NNODES * HIDDIM);
    for (int hd = 0; hd < NHEADS; ++hd) {
        const unsigned short* Wh = Wt3 + (size_t)hd * 384 * KC;
        gemm_mfma_kernel<float><<<g1, 256, 0, stream>>>(Acat, Wh, b3cat + hd * 384,
                                                        qb, 128, NNODES);
        gemm_mfma_kernel<unsigned short><<<g2, 256, 0, stream>>>(
            Acat, Wh + (size_t)128 * KC, b3cat + hd * 384 + 128, kvbuf, 256, NNODES);
        attn_big_kernel<<<NNODES, 64, 0, stream>>>(qb, kvbuf, offs, csrsrc, hbuf);
    }
    gemm_mfma_kernel<float><<<g1, 256, 0, stream>>>(Acat, Ws3t, bs3, sb, 128, NNODES);
    beta3_kernel<<<NNODES, 128, 0, stream>>>(hbuf, sb, Wbeta3);
    float* st3 = bnstat4 + 3 * 256;
    bn_stats_kernel<<<200, 128, 0, stream>>>(hbuf, st3, NNODES);
    bn_apply_kernel<<<256, 128, 0, stream>>>(hbuf, st3, bn_gamma + 3 * HIDDIM,
                                             bn_beta + 3 * HIDDIM, NNODES, (unsigned short*)0);

    // ---- global mean pool ----
    pool_kernel<<<NGRAPH, 256, 0, stream>>>(hbuf, gs, ge, out);
}

// Round 4
// 927.203 us; speedup vs baseline: 2.8412x; 1.4300x over previous
//
#include <hip/hip_runtime.h>
#include <math.h>

#define NNODES 20000
#define NPAD   20096   // 157 * 128
#define NEDGES 160000
#define HIDDIM 128
#define NHEADS 8
#define NGRAPH 64
#define KC 384   // concatenated K (hi | lo | hi)

typedef short short8 __attribute__((ext_vector_type(8)));
typedef float floatx4 __attribute__((ext_vector_type(4)));

__device__ inline unsigned short f2bf(float x) {
    unsigned u = __float_as_uint(x);
    u += 0x7fff + ((u >> 16) & 1);
    return (unsigned short)(u >> 16);
}
__device__ inline float bf2f(unsigned short h) {
    return __uint_as_float(((unsigned)h) << 16);
}

// ---------------- utility ----------------
__global__ __launch_bounds__(256) void zero_kernel(float* __restrict__ p, int n) {
    int i = blockIdx.x * blockDim.x + threadIdx.x;
    if (i < n) p[i] = 0.f;
}

// ---------------- CSR build ----------------
__global__ __launch_bounds__(256) void count_deg_kernel(const int* __restrict__ dst,
                                                        int* __restrict__ deg, int e) {
    int i = blockIdx.x * blockDim.x + threadIdx.x;
    if (i < e) atomicAdd(&deg[dst[i]], 1);
}

__global__ __launch_bounds__(256) void scan1_kernel(const int* __restrict__ deg,
                                                    int* __restrict__ chunk,
                                                    int* __restrict__ bsum, int n) {
    __shared__ int buf[256];
    int t = threadIdx.x;
    int i = blockIdx.x * 256 + t;
    int v = (i < n) ? deg[i] : 0;
    buf[t] = v;
    __syncthreads();
    for (int off = 1; off < 256; off <<= 1) {
        int tmp = (t >= off) ? buf[t - off] : 0;
        __syncthreads();
        buf[t] += tmp;
        __syncthreads();
    }
    if (i < n) chunk[i] = buf[t];
    if (t == 255) bsum[blockIdx.x] = buf[255];
}

__global__ __launch_bounds__(128) void scan2_kernel(int* __restrict__ bsum, int nb) {
    __shared__ int buf[128];
    int t = threadIdx.x;
    int v = (t < nb) ? bsum[t] : 0;
    buf[t] = v;
    __syncthreads();
    for (int off = 1; off < 128; off <<= 1) {
        int tmp = (t >= off) ? buf[t - off] : 0;
        __syncthreads();
        buf[t] += tmp;
        __syncthreads();
    }
    if (t < nb) bsum[t] = buf[t] - v;
}

__global__ __launch_bounds__(256) void scan3_kernel(const int* __restrict__ chunk,
                                                    const int* __restrict__ bsum,
                                                    int* __restrict__ offs, int n) {
    int i = blockIdx.x * 256 + threadIdx.x;
    if (i < n) offs[i + 1] = chunk[i] + bsum[i >> 8];
    if (i == 0) offs[0] = 0;
}

__global__ __launch_bounds__(256) void scatter_kernel(const int* __restrict__ src,
                                                      const int* __restrict__ dst,
                                                      const int* __restrict__ offs,
                                                      int* __restrict__ cursor,
                                                      int* __restrict__ csr_src, int e) {
    int i = blockIdx.x * blockDim.x + threadIdx.x;
    if (i < e) {
        int d = dst[i];
        int pos = offs[d] + atomicAdd(&cursor[d], 1);
        csr_src[pos] = src[i];
    }
}

// ---------------- weight prep ----------------
// rows: [0,1536): layers0-2 (li*512 + n, order q|s|k|v)
// [1536,1664): Wp ; [1664,1792): Ws3
// [1792,2816): layer3 q (h*128+j) ; [2816,4864): layer3 kv (h*256 + {k:j, v:128+j})
__global__ __launch_bounds__(128) void prep_w_kernel(
    const float* __restrict__ Wq, const float* __restrict__ Wk,
    const float* __restrict__ Wv, const float* __restrict__ Ws,
    const float* __restrict__ Wp, const float* __restrict__ Ws3,
    const float* __restrict__ Wq3, const float* __restrict__ Wk3,
    const float* __restrict__ Wv3, unsigned short* __restrict__ WtAll) {
    int id = blockIdx.x;
    int k = threadIdx.x;
    float w;
    if (id < 1536) {
        int li = id / 512, n = id % 512, sel = n >> 7, np = n & 127;
        const float* W = (sel == 0) ? Wq : (sel == 1) ? Ws : (sel == 2) ? Wk : Wv;
        w = W[li * 16384 + k * 128 + np];
    } else if (id < 1664) {
        w = Wp[k * 128 + (id - 1536)];
    } else if (id < 1792) {
        w = Ws3[k * 128 + (id - 1664)];
    } else if (id < 2816) {
        int r = id - 1792, h = r >> 7, j = r & 127;
        w = Wq3[k * 1024 + h * 128 + j];
    } else {
        int r = id - 2816, h = r >> 8, jj = r & 255;
        const float* W = (jj < 128) ? Wk3 : Wv3;
        w = W[k * 1024 + h * 128 + (jj & 127)];
    }
    unsigned short hi = f2bf(w);
    unsigned short lo = f2bf(w - bf2f(hi));
    unsigned short* dst = WtAll + (size_t)id * KC;
    dst[k] = hi;
    dst[128 + k] = hi;
    dst[256 + k] = lo;
}

__global__ __launch_bounds__(256) void prep_bias_kernel(
    const float* __restrict__ bq, const float* __restrict__ bk,
    const float* __restrict__ bv, const float* __restrict__ bs,
    const float* __restrict__ bq3, const float* __restrict__ bk3,
    const float* __restrict__ bv3, float* __restrict__ bcat) {
    int id = blockIdx.x * 256 + threadIdx.x;
    if (id >= 4608) return;
    float v;
    if (id < 1536) {
        int li = id / 512, n = id % 512, sel = n >> 7, np = n & 127;
        const float* b = (sel == 0) ? bq : (sel == 1) ? bs : (sel == 2) ? bk : bv;
        v = b[li * 128 + np];
    } else if (id < 2560) {
        int r = id - 1536;
        v = bq3[r];
    } else {
        int r = id - 2560, h = r >> 8, jj = r & 255;
        const float* b = (jj < 128) ? bk3 : bv3;
        v = b[h * 128 + (jj & 127)];
    }
    bcat[id] = v;
}

// ---------------- activation -> split-bf16 A_cat ----------------
__global__ __launch_bounds__(256) void cat_from_kernel(const float* __restrict__ h,
                                                       unsigned short* __restrict__ Acat) {
    int idx = blockIdx.x * 256 + threadIdx.x;
    if (idx >= NPAD * HIDDIM) return;
    int r = idx >> 7, k = idx & 127;
    float x = (r < NNODES) ? h[idx] : 0.f;
    unsigned short hi = f2bf(x);
    unsigned short lo = f2bf(x - bf2f(hi));
    unsigned short* row = Acat + (size_t)r * KC;
    row[k] = hi;
    row[128 + k] = lo;
    row[256 + k] = hi;
}

// ---------------- MFMA GEMM ----------------
// grid (NPAD/128, M/128), 4 waves; each wave one 64x64 patch (4x4 of 16x16x32).
// KG=12: full split (hi.hi + lo.hi + hi.lo). KG=8: drop hi.lo (bf16-out GEMMs).
template <typename OutT, int KG>
__global__ __launch_bounds__(256) void gemm_mfma_kernel(
    const unsigned short* __restrict__ Acat, const unsigned short* __restrict__ Wt,
    const float* __restrict__ bias, OutT* __restrict__ C, int M, int nrows) {
    int lane = threadIdx.x & 63;
    int wave = threadIdx.x >> 6;
    int rowBase = blockIdx.x * 128 + (wave & 1) * 64;
    int colBase = blockIdx.y * 128 + (wave >> 1) * 64;
    int m = lane & 15;
    int ko = (lane >> 4) * 8;
    const unsigned short* aptr = Acat + (size_t)(rowBase + m) * KC + ko;
    const unsigned short* bptr = Wt + (size_t)(colBase + m) * KC + ko;
    floatx4 acc[4][4];
#pragma unroll
    for (int r = 0; r < 4; ++r)
#pragma unroll
        for (int c = 0; c < 4; ++c) acc[r][c] = (floatx4){0.f, 0.f, 0.f, 0.f};
#pragma unroll
    for (int kg = 0; kg < KG; ++kg) {
        short8 a[4], b[4];
#pragma unroll
        for (int r = 0; r < 4; ++r) a[r] = *(const short8*)(aptr + (size_t)r * 16 * KC + kg * 32);
#pragma unroll
        for (int c = 0; c < 4; ++c) b[c] = *(const short8*)(bptr + (size_t)c * 16 * KC + kg * 32);
#pragma unroll
        for (int r = 0; r < 4; ++r)
#pragma unroll
            for (int c = 0; c < 4; ++c)
                acc[r][c] = __builtin_amdgcn_mfma_f32_16x16x32_bf16(a[r], b[c], acc[r][c], 0, 0, 0);
    }
    int r0 = rowBase + (lane >> 4) * 4;
#pragma unroll
    for (int c = 0; c < 4; ++c) {
        int col = colBase + c * 16 + m;
        float bv = bias[col];
#pragma unroll
        for (int r = 0; r < 4; ++r) {
#pragma unroll
            for (int j = 0; j < 4; ++j) {
                int row = r0 + r * 16 + j;
                if (row < nrows) {
                    float val = acc[r][c][j] + bv;
                    if (sizeof(OutT) == 2)
                        ((unsigned short*)C)[(size_t)row * M + col] = f2bf(val);
                    else
                        ((float*)C)[(size_t)row * M + col] = val;
                }
            }
        }
    }
}

// ---------------- attention layers 0-2 (8 heads x d=16) + beta gate, 1 wave ----------------
// qs: [N][256] fp32 (q|s) ; kv: [N][256] bf16 (k|v). lane l -> dims 2l,2l+1; head = l>>3.
__global__ __launch_bounds__(64) void attn_small_kernel(
    const float* __restrict__ qs, const unsigned short* __restrict__ kv,
    const float* __restrict__ Wb,
    const int* __restrict__ offs, const int* __restrict__ csr_src,
    float* __restrict__ out) {
    int i = blockIdx.x;
    int l = threadIdx.x;
    float2 qv = *(const float2*)(qs + (size_t)i * 256 + 2 * l);
    int e0 = offs[i], e1 = offs[i + 1];
    float mm = -1e30f, lac = 0.f, ax = 0.f, ay = 0.f;
    for (int e = e0; e < e1; ++e) {
        int sn = csr_src[e];
        const unsigned short* row = kv + (size_t)sn * 256;
        unsigned kk = *(const unsigned*)(row + 2 * l);
        unsigned vv = *(const unsigned*)(row + 128 + 2 * l);
        float kx = bf2f((unsigned short)(kk & 0xffff)), ky = bf2f((unsigned short)(kk >> 16));
        float vx = bf2f((unsigned short)(vv & 0xffff)), vy = bf2f((unsigned short)(vv >> 16));
        float p = qv.x * kx + qv.y * ky;
        p += __shfl_xor(p, 1);
        p += __shfl_xor(p, 2);
        p += __shfl_xor(p, 4);       // dot over this head's 8 lanes (16 dims)
        float logit = p * 0.25f;     // 1/sqrt(16)
        float mnew = fmaxf(mm, logit);
        float sc = __expf(mm - mnew);
        float w = __expf(logit - mnew);
        ax = ax * sc + w * vx;
        ay = ay * sc + w * vy;
        lac = lac * sc + w;
        mm = mnew;
    }
    float inv = 1.f / (lac + 1e-16f);
    float ox = ax * inv, oy = ay * inv;
    float2 rv = *(const float2*)(qs + (size_t)i * 256 + 128 + 2 * l);
    float part = ox * Wb[2 * l] + oy * Wb[2 * l + 1]
               + rv.x * Wb[128 + 2 * l] + rv.y * Wb[128 + 2 * l + 1]
               + (ox - rv.x) * Wb[256 + 2 * l] + (oy - rv.y) * Wb[256 + 2 * l + 1];
#pragma unroll
    for (int msk = 1; msk <= 32; msk <<= 1) part += __shfl_xor(part, msk);
    float g = 1.f / (1.f + __expf(-part));
    float2 o2 = {g * rv.x + (1.f - g) * ox, g * rv.y + (1.f - g) * oy};
    *(float2*)(out + (size_t)i * HIDDIM + 2 * l) = o2;
}

// ---------------- attention layer 3, 4 heads per pass (d=128), 1 wave ----------------
// q3: [N][512] fp32 ; kv3: [N][1024] bf16 (per head: k|v) ; obuf3: [4][N][128]
__global__ __launch_bounds__(64) void attn_big3_kernel(
    const float* __restrict__ q3, const unsigned short* __restrict__ kv3,
    const int* __restrict__ offs, const int* __restrict__ csr_src,
    float* __restrict__ obuf3, int accumulate) {
    int i = blockIdx.x;
    int y = blockIdx.y;   // head within pass
    int t = threadIdx.x;  // dims 2t, 2t+1
    float2 qv = *(const float2*)(q3 + (size_t)i * 512 + y * 128 + 2 * t);
    int e0 = offs[i], e1 = offs[i + 1];
    float mm = -1e30f, lac = 0.f, ax = 0.f, ay = 0.f;
    for (int e = e0; e < e1; ++e) {
        int sn = csr_src[e];
        const unsigned short* row = kv3 + (size_t)sn * 1024 + y * 256;
        unsigned kk = *(const unsigned*)(row + 2 * t);
        unsigned vv = *(const unsigned*)(row + 128 + 2 * t);
        float kx = bf2f((unsigned short)(kk & 0xffff)), ky = bf2f((unsigned short)(kk >> 16));
        float vx = bf2f((unsigned short)(vv & 0xffff)), vy = bf2f((unsigned short)(vv >> 16));
        float p = qv.x * kx + qv.y * ky;
#pragma unroll
        for (int msk = 1; msk <= 32; msk <<= 1) p += __shfl_xor(p, msk);
        float logit = p * 0.08838834764831845f;  // 1/sqrt(128)
        float mnew = fmaxf(mm, logit);
        float sc = __expf(mm - mnew);
        float w = __expf(logit - mnew);
        ax = ax * sc + w * vx;
        ay = ay * sc + w * vy;
        lac = lac * sc + w;
        mm = mnew;
    }
    float inv = 1.f / (lac + 1e-16f);
    float* o = obuf3 + ((size_t)y * NNODES + i) * HIDDIM + 2 * t;
    if (accumulate) {
        o[0] += ax * inv;
        o[1] += ay * inv;
    } else {
        o[0] = ax * inv;
        o[1] = ay * inv;
    }
}

// ---------------- beta gate layer 3 (head mean over obuf3) ----------------
__global__ __launch_bounds__(128) void beta3_kernel(const float* __restrict__ obuf3,
                                                    const float* __restrict__ s,
                                                    const float* __restrict__ Wb,
                                                    float* __restrict__ out) {
    int i = blockIdx.x, t = threadIdx.x;
    float o = 0.f;
#pragma unroll
    for (int y = 0; y < 4; ++y) o += obuf3[((size_t)y * NNODES + i) * HIDDIM + t];
    o *= 0.125f;
    float r = s[(size_t)i * HIDDIM + t];
    float part = o * Wb[t] + r * Wb[128 + t] + (o - r) * Wb[256 + t];
#pragma unroll
    for (int msk = 1; msk <= 32; msk <<= 1) part += __shfl_xor(part, msk);
    __shared__ float wsum[2];
    if ((t & 63) == 0) wsum[t >> 6] = part;
    __syncthreads();
    float tot = wsum[0] + wsum[1];
    float g = 1.f / (1.f + __expf(-tot));
    out[(size_t)i * HIDDIM + t] = g * r + (1.f - g) * o;
}

// ---------------- batchnorm ----------------
__global__ __launch_bounds__(128) void bn_stats_kernel(const float* __restrict__ x,
                                                       float* __restrict__ stat, int n) {
    int t = threadIdx.x;
    float s = 0.f, sq = 0.f;
    for (int i = blockIdx.x; i < n; i += gridDim.x) {
        float v = x[(size_t)i * HIDDIM + t];
        s += v;
        sq += v * v;
    }
    atomicAdd(&stat[t], s);
    atomicAdd(&stat[HIDDIM + t], sq);
}

__global__ __launch_bounds__(128) void bn_apply_kernel(float* __restrict__ x,
                                                       const float* __restrict__ stat,
                                                       const float* __restrict__ gamma,
                                                       const float* __restrict__ beta, int n,
                                                       unsigned short* __restrict__ cat) {
    int t = threadIdx.x;
    float mu = stat[t] / (float)n;
    float var = stat[HIDDIM + t] / (float)n - mu * mu;
    float rs = rsqrtf(var + 1e-5f);
    float g = gamma[t], b = beta[t];
    for (int i = blockIdx.x; i < n; i += gridDim.x) {
        float v = x[(size_t)i * HIDDIM + t];
        v = fmaxf((v - mu) * rs * g + b, 0.f);
        x[(size_t)i * HIDDIM + t] = v;
        if (cat) {
            unsigned short hi = f2bf(v);
            unsigned short lo = f2bf(v - bf2f(hi));
            unsigned short* row = cat + (size_t)i * KC;
            row[t] = hi;
            row[128 + t] = lo;
            row[256 + t] = hi;
        }
    }
}

// ---------------- pool ----------------
__global__ __launch_bounds__(256) void gb_kernel(const int* __restrict__ batch,
                                                 int* __restrict__ gs,
                                                 int* __restrict__ ge, int n) {
    int i = blockIdx.x * 256 + threadIdx.x;
    if (i >= n) return;
    int b = batch[i];
    if (i == 0 || batch[i - 1] != b) gs[b] = i;
    if (i == n - 1 || batch[i + 1] != b) ge[b] = i + 1;
}

// grid (NGRAPH, 8): chunk c covers rows s + (2j + half) interleaved by 16
__global__ __launch_bounds__(256) void pool_part_kernel(const float* __restrict__ x,
                                                        const int* __restrict__ gs,
                                                        const int* __restrict__ ge,
                                                        float* __restrict__ out) {
    int g = blockIdx.x, c = blockIdx.y;
    int t = threadIdx.x;
    int f = t & 127, half = t >> 7;
    int s = gs[g], e = ge[g];
    float acc = 0.f;
    for (int i = s + 2 * c + half; i < e; i += 16) acc += x[(size_t)i * HIDDIM + f];
    __shared__ float l0[128];
    if (half == 0) l0[f] = acc;
    __syncthreads();
    if (half == 1) atomicAdd(&out[g * HIDDIM + f], l0[f] + acc);
}

__global__ __launch_bounds__(128) void pool_div_kernel(float* __restrict__ out,
                                                       const int* __restrict__ gs,
                                                       const int* __restrict__ ge) {
    int g = blockIdx.x, t = threadIdx.x;
    int c = ge[g] - gs[g];
    out[g * HIDDIM + t] /= (float)(c > 0 ? c : 1);
}

// ---------------- host ----------------
extern "C" void kernel_launch(void* const* d_in, const int* in_sizes, int n_in,
                              void* d_out, int out_size, void* d_ws, size_t ws_size,
                              hipStream_t stream) {
    const float* x       = (const float*)d_in[0];
    const int*   ei      = (const int*)d_in[1];
    const int*   batch   = (const int*)d_in[2];
    const float* Wp      = (const float*)d_in[3];
    const float* bp      = (const float*)d_in[4];
    const float* Wq      = (const float*)d_in[5];
    const float* bq      = (const float*)d_in[6];
    const float* Wk      = (const float*)d_in[7];
    const float* bk      = (const float*)d_in[8];
    const float* Wv      = (const float*)d_in[9];
    const float* bv      = (const float*)d_in[10];
    const float* Ws      = (const float*)d_in[11];
    const float* bs      = (const float*)d_in[12];
    const float* Wbeta   = (const float*)d_in[13];
    const float* Wq3     = (const float*)d_in[14];
    const float* bq3     = (const float*)d_in[15];
    const float* Wk3     = (const float*)d_in[16];
    const float* bk3     = (const float*)d_in[17];
    const float* Wv3     = (const float*)d_in[18];
    const float* bv3     = (const float*)d_in[19];
    const float* Ws3     = (const float*)d_in[20];
    const float* bs3     = (const float*)d_in[21];
    const float* Wbeta3  = (const float*)d_in[22];
    const float* bn_gamma = (const float*)d_in[23];
    const float* bn_beta  = (const float*)d_in[24];
    float* out = (float*)d_out;

    const int* esrc = ei;
    const int* edst = ei + NEDGES;

    char* wpc = (char*)d_ws;
    auto alloc = [&](size_t nbytes) -> char* {
        char* p = wpc;
        wpc += (nbytes + 255) & ~(size_t)255;
        return p;
    };
    unsigned short* Acat  = (unsigned short*)alloc((size_t)NPAD * KC * 2);     // 15.4 MB
    unsigned short* WtAll = (unsigned short*)alloc((size_t)4864 * KC * 2);     // 3.7 MB
    float* bcat   = (float*)alloc(4608 * 4);
    float* qsbuf  = (float*)alloc((size_t)NNODES * 512 * 4);                   // 41 MB (q|s / layer3 q3)
    unsigned short* kvbuf = (unsigned short*)alloc((size_t)NNODES * 1024 * 2); // 41 MB (k|v / layer3 kv3)
    float* obuf3  = (float*)alloc((size_t)4 * NNODES * HIDDIM * 4);            // 41 MB
    float* hbuf   = (float*)alloc((size_t)NNODES * HIDDIM * 4);
    float* obuf   = (float*)alloc((size_t)NNODES * HIDDIM * 4);
    float* sb     = (float*)alloc((size_t)NNODES * HIDDIM * 4);
    int*   deg    = (int*)alloc((2 * NNODES + 128 + 4 * 256) * 4);
    int*   cursor = deg + NNODES;
    int*   gs     = deg + 2 * NNODES;
    int*   ge     = gs + NGRAPH;
    float* bnstat4 = (float*)(deg + 2 * NNODES + 128);
    int*   chunk  = (int*)alloc(NNODES * 4);
    int*   bsum   = (int*)alloc(128 * 4);
    int*   offs   = (int*)alloc((NNODES + 1) * 4);
    int*   csrsrc = (int*)alloc(NEDGES * 4);

    unsigned short* WtL   = WtAll;                      // [3][512][KC] rows q|s|k|v
    unsigned short* Wpt   = WtAll + (size_t)1536 * KC;
    unsigned short* Ws3t  = WtAll + (size_t)1664 * KC;
    unsigned short* Wt3q  = WtAll + (size_t)1792 * KC;  // [8][128][KC]
    unsigned short* Wt3kv = WtAll + (size_t)2816 * KC;  // [8][256][KC]
    float* bcatL = bcat;
    float* b3q   = bcat + 1536;   // [1024]
    float* b3kv  = bcat + 2560;   // [2048]

    const int TB = 256;
    const int ZWORDS = 2 * NNODES + 128 + 4 * 256;
    zero_kernel<<<(ZWORDS + TB - 1) / TB, TB, 0, stream>>>((float*)deg, ZWORDS);
    // ---- CSR ----
    count_deg_kernel<<<(NEDGES + TB - 1) / TB, TB, 0, stream>>>(edst, deg, NEDGES);
    const int NB = (NNODES + 255) / 256;  // 79
    scan1_kernel<<<NB, 256, 0, stream>>>(deg, chunk, bsum, NNODES);
    scan2_kernel<<<1, 128, 0, stream>>>(bsum, NB);
    scan3_kernel<<<NB, 256, 0, stream>>>(chunk, bsum, offs, NNODES);
    scatter_kernel<<<(NEDGES + TB - 1) / TB, TB, 0, stream>>>(esrc, edst, offs, cursor, csrsrc, NEDGES);
    gb_kernel<<<(NNODES + TB - 1) / TB, TB, 0, stream>>>(batch, gs, ge, NNODES);

    // ---- weight/bias prep ----
    prep_w_kernel<<<4864, 128, 0, stream>>>(Wq, Wk, Wv, Ws, Wp, Ws3, Wq3, Wk3, Wv3, WtAll);
    prep_bias_kernel<<<(4608 + TB - 1) / TB, TB, 0, stream>>>(bq, bk, bv, bs, bq3, bk3, bv3, bcat);

    const int CATB = (NPAD * HIDDIM + TB - 1) / TB;
    const int GX = NPAD / 128;  // 157

    // ---- initial projection ----
    cat_from_kernel<<<CATB, TB, 0, stream>>>(x, Acat);
    gemm_mfma_kernel<float, 12><<<dim3(GX, 1), 256, 0, stream>>>(Acat, Wpt, bp, hbuf, 128, NNODES);
    cat_from_kernel<<<CATB, TB, 0, stream>>>(hbuf, Acat);

    // ---- layers 0..2 ----
    for (int li = 0; li < 3; ++li) {
        const unsigned short* Wl = WtL + (size_t)li * 512 * KC;
        gemm_mfma_kernel<float, 12><<<dim3(GX, 2), 256, 0, stream>>>(
            Acat, Wl, bcatL + li * 512, qsbuf, 256, NNODES);
        gemm_mfma_kernel<unsigned short, 8><<<dim3(GX, 2), 256, 0, stream>>>(
            Acat, Wl + (size_t)256 * KC, bcatL + li * 512 + 256, kvbuf, 256, NNODES);
        attn_small_kernel<<<NNODES, 64, 0, stream>>>(qsbuf, kvbuf, Wbeta + li * 384,
                                                     offs, csrsrc, obuf);
        float* st = bnstat4 + li * 256;
        bn_stats_kernel<<<640, 128, 0, stream>>>(obuf, st, NNODES);
        bn_apply_kernel<<<512, 128, 0, stream>>>(obuf, st, bn_gamma + li * HIDDIM,
                                                 bn_beta + li * HIDDIM, NNODES, Acat);
    }

    // ---- layer 3: two passes of 4 heads ----
    for (int h2 = 0; h2 < 2; ++h2) {
        gemm_mfma_kernel<float, 12><<<dim3(GX, 4), 256, 0, stream>>>(
            Acat, Wt3q + (size_t)h2 * 512 * KC, b3q + h2 * 512, qsbuf, 512, NNODES);
        gemm_mfma_kernel<unsigned short, 8><<<dim3(GX, 8), 256, 0, stream>>>(
            Acat, Wt3kv + (size_t)h2 * 1024 * KC, b3kv + h2 * 1024, kvbuf, 1024, NNODES);
        attn_big3_kernel<<<dim3(NNODES, 4), 64, 0, stream>>>(qsbuf, kvbuf, offs, csrsrc,
                                                             obuf3, h2);
    }
    gemm_mfma_kernel<float, 12><<<dim3(GX, 1), 256, 0, stream>>>(Acat, Ws3t, bs3, sb, 128, NNODES);
    beta3_kernel<<<NNODES, 128, 0, stream>>>(obuf3, sb, Wbeta3, hbuf);
    float* st3 = bnstat4 + 3 * 256;
    bn_stats_kernel<<<640, 128, 0, stream>>>(hbuf, st3, NNODES);
    bn_apply_kernel<<<512, 128, 0, stream>>>(hbuf, st3, bn_gamma + 3 * HIDDIM,
                                             bn_beta + 3 * HIDDIM, NNODES, (unsigned short*)0);

    // ---- global mean pool ----
    zero_kernel<<<(NGRAPH * HIDDIM + TB - 1) / TB, TB, 0, stream>>>(out, NGRAPH * HIDDIM);
    pool_part_kernel<<<dim3(NGRAPH, 8), 256, 0, stream>>>(hbuf, gs, ge, out);
    pool_div_kernel<<<NGRAPH, 128, 0, stream>>>(out, gs, ge);
}

// Round 5
// 884.933 us; speedup vs baseline: 2.9769x; 1.0478x over previous
//
#include <hip/hip_runtime.h>
#include <math.h>

#define NNODES 20000
#define NPAD   20096   // 157 * 128
#define NEDGES 160000
#define HIDDIM 128
#define NHEADS 8
#define NGRAPH 64
#define KC 384   // concatenated K (hi | lo | hi)

typedef short short8 __attribute__((ext_vector_type(8)));
typedef float floatx4 __attribute__((ext_vector_type(4)));

__device__ inline unsigned short f2bf(float x) {
    unsigned u = __float_as_uint(x);
    u += 0x7fff + ((u >> 16) & 1);
    return (unsigned short)(u >> 16);
}
__device__ inline float bf2f(unsigned short h) {
    return __uint_as_float(((unsigned)h) << 16);
}

// ---------------- utility ----------------
__global__ __launch_bounds__(256) void zero_kernel(float* __restrict__ p, int n) {
    int i = blockIdx.x * blockDim.x + threadIdx.x;
    if (i < n) p[i] = 0.f;
}

// ---------------- CSR build ----------------
__global__ __launch_bounds__(256) void count_deg_kernel(const int* __restrict__ dst,
                                                        int* __restrict__ deg, int e) {
    int i = blockIdx.x * blockDim.x + threadIdx.x;
    if (i < e) atomicAdd(&deg[dst[i]], 1);
}

__global__ __launch_bounds__(256) void scan1_kernel(const int* __restrict__ deg,
                                                    int* __restrict__ chunk,
                                                    int* __restrict__ bsum, int n) {
    __shared__ int buf[256];
    int t = threadIdx.x;
    int i = blockIdx.x * 256 + t;
    int v = (i < n) ? deg[i] : 0;
    buf[t] = v;
    __syncthreads();
    for (int off = 1; off < 256; off <<= 1) {
        int tmp = (t >= off) ? buf[t - off] : 0;
        __syncthreads();
        buf[t] += tmp;
        __syncthreads();
    }
    if (i < n) chunk[i] = buf[t];
    if (t == 255) bsum[blockIdx.x] = buf[255];
}

__global__ __launch_bounds__(128) void scan2_kernel(int* __restrict__ bsum, int nb) {
    __shared__ int buf[128];
    int t = threadIdx.x;
    int v = (t < nb) ? bsum[t] : 0;
    buf[t] = v;
    __syncthreads();
    for (int off = 1; off < 128; off <<= 1) {
        int tmp = (t >= off) ? buf[t - off] : 0;
        __syncthreads();
        buf[t] += tmp;
        __syncthreads();
    }
    if (t < nb) bsum[t] = buf[t] - v;
}

__global__ __launch_bounds__(256) void scan3_kernel(const int* __restrict__ chunk,
                                                    const int* __restrict__ bsum,
                                                    int* __restrict__ offs, int n) {
    int i = blockIdx.x * 256 + threadIdx.x;
    if (i < n) offs[i + 1] = chunk[i] + bsum[i >> 8];
    if (i == 0) offs[0] = 0;
}

__global__ __launch_bounds__(256) void scatter_kernel(const int* __restrict__ src,
                                                      const int* __restrict__ dst,
                                                      const int* __restrict__ offs,
                                                      int* __restrict__ cursor,
                                                      int* __restrict__ csr_src, int e) {
    int i = blockIdx.x * blockDim.x + threadIdx.x;
    if (i < e) {
        int d = dst[i];
        int pos = offs[d] + atomicAdd(&cursor[d], 1);
        csr_src[pos] = src[i];
    }
}

// ---------------- weight prep ----------------
__global__ __launch_bounds__(128) void prep_w_kernel(
    const float* __restrict__ Wq, const float* __restrict__ Wk,
    const float* __restrict__ Wv, const float* __restrict__ Ws,
    const float* __restrict__ Wp, const float* __restrict__ Ws3,
    const float* __restrict__ Wq3, const float* __restrict__ Wk3,
    const float* __restrict__ Wv3, unsigned short* __restrict__ WtAll) {
    int id = blockIdx.x;
    int k = threadIdx.x;
    float w;
    if (id < 1536) {
        int li = id / 512, n = id % 512, sel = n >> 7, np = n & 127;
        const float* W = (sel == 0) ? Wq : (sel == 1) ? Ws : (sel == 2) ? Wk : Wv;
        w = W[li * 16384 + k * 128 + np];
    } else if (id < 1664) {
        w = Wp[k * 128 + (id - 1536)];
    } else if (id < 1792) {
        w = Ws3[k * 128 + (id - 1664)];
    } else if (id < 2816) {
        int r = id - 1792, h = r >> 7, j = r & 127;
        w = Wq3[k * 1024 + h * 128 + j];
    } else {
        int r = id - 2816, h = r >> 8, jj = r & 255;
        const float* W = (jj < 128) ? Wk3 : Wv3;
        w = W[k * 1024 + h * 128 + (jj & 127)];
    }
    unsigned short hi = f2bf(w);
    unsigned short lo = f2bf(w - bf2f(hi));
    unsigned short* dst = WtAll + (size_t)id * KC;
    dst[k] = hi;
    dst[128 + k] = hi;
    dst[256 + k] = lo;
}

__global__ __launch_bounds__(256) void prep_bias_kernel(
    const float* __restrict__ bq, const float* __restrict__ bk,
    const float* __restrict__ bv, const float* __restrict__ bs,
    const float* __restrict__ bq3, const float* __restrict__ bk3,
    const float* __restrict__ bv3, float* __restrict__ bcat) {
    int id = blockIdx.x * 256 + threadIdx.x;
    if (id >= 4608) return;
    float v;
    if (id < 1536) {
        int li = id / 512, n = id % 512, sel = n >> 7, np = n & 127;
        const float* b = (sel == 0) ? bq : (sel == 1) ? bs : (sel == 2) ? bk : bv;
        v = b[li * 128 + np];
    } else if (id < 2560) {
        v = bq3[id - 1536];
    } else {
        int r = id - 2560, h = r >> 8, jj = r & 255;
        const float* b = (jj < 128) ? bk3 : bv3;
        v = b[h * 128 + (jj & 127)];
    }
    bcat[id] = v;
}

// ---------------- activation -> split-bf16 A_cat ----------------
__global__ __launch_bounds__(256) void cat_from_kernel(const float* __restrict__ h,
                                                       unsigned short* __restrict__ Acat) {
    int idx = blockIdx.x * 256 + threadIdx.x;
    if (idx >= NPAD * HIDDIM) return;
    int r = idx >> 7, k = idx & 127;
    float x = (r < NNODES) ? h[idx] : 0.f;
    unsigned short hi = f2bf(x);
    unsigned short lo = f2bf(x - bf2f(hi));
    unsigned short* row = Acat + (size_t)r * KC;
    row[k] = hi;
    row[128 + k] = lo;
    row[256 + k] = hi;
}

// ---------------- MFMA GEMM (column tile fast-varying for A-tile L2 reuse) ----------------
template <typename OutT, int KG>
__global__ __launch_bounds__(256) void gemm_mfma_kernel(
    const unsigned short* __restrict__ Acat, const unsigned short* __restrict__ Wt,
    const float* __restrict__ bias, OutT* __restrict__ C, int M, int nrows) {
    int lane = threadIdx.x & 63;
    int wave = threadIdx.x >> 6;
    int rowBase = blockIdx.y * 128 + (wave & 1) * 64;
    int colBase = blockIdx.x * 128 + (wave >> 1) * 64;
    int m = lane & 15;
    int ko = (lane >> 4) * 8;
    const unsigned short* aptr = Acat + (size_t)(rowBase + m) * KC + ko;
    const unsigned short* bptr = Wt + (size_t)(colBase + m) * KC + ko;
    floatx4 acc[4][4];
#pragma unroll
    for (int r = 0; r < 4; ++r)
#pragma unroll
        for (int c = 0; c < 4; ++c) acc[r][c] = (floatx4){0.f, 0.f, 0.f, 0.f};
#pragma unroll
    for (int kg = 0; kg < KG; ++kg) {
        short8 a[4], b[4];
#pragma unroll
        for (int r = 0; r < 4; ++r) a[r] = *(const short8*)(aptr + (size_t)r * 16 * KC + kg * 32);
#pragma unroll
        for (int c = 0; c < 4; ++c) b[c] = *(const short8*)(bptr + (size_t)c * 16 * KC + kg * 32);
#pragma unroll
        for (int r = 0; r < 4; ++r)
#pragma unroll
            for (int c = 0; c < 4; ++c)
                acc[r][c] = __builtin_amdgcn_mfma_f32_16x16x32_bf16(a[r], b[c], acc[r][c], 0, 0, 0);
    }
    int r0 = rowBase + (lane >> 4) * 4;
#pragma unroll
    for (int c = 0; c < 4; ++c) {
        int col = colBase + c * 16 + m;
        float bv = bias[col];
#pragma unroll
        for (int r = 0; r < 4; ++r) {
#pragma unroll
            for (int j = 0; j < 4; ++j) {
                int row = r0 + r * 16 + j;
                if (row < nrows) {
                    float val = acc[r][c][j] + bv;
                    if (sizeof(OutT) == 2)
                        ((unsigned short*)C)[(size_t)row * M + col] = f2bf(val);
                    else
                        ((float*)C)[(size_t)row * M + col] = val;
                }
            }
        }
    }
}

// ---------------- attention layers 0-2: 2 edge slots x (8 heads x 4 lanes) ----------------
__global__ __launch_bounds__(64) void attn_small_kernel(
    const float* __restrict__ qs, const unsigned short* __restrict__ kv,
    const float* __restrict__ Wb,
    const int* __restrict__ offs, const int* __restrict__ csr_src,
    float* __restrict__ out) {
    int i = blockIdx.x;
    int l = threadIdx.x;
    int g = l >> 5;
    int d0 = (l & 31) * 4;  // head*16 + 4*s
    float4 qv = *(const float4*)(qs + (size_t)i * 256 + d0);
    int e0 = offs[i], e1 = offs[i + 1];
    float mm = -1e30f, lac = 0.f;
    float a0 = 0.f, a1 = 0.f, a2 = 0.f, a3 = 0.f;
    for (int e = e0 + g; e < e1; e += 2) {
        int sn = csr_src[e];
        const unsigned short* row = kv + (size_t)sn * 256;
        uint2 kk = *(const uint2*)(row + d0);
        uint2 vv = *(const uint2*)(row + 128 + d0);
        float k0 = bf2f((unsigned short)(kk.x & 0xffff)), k1 = bf2f((unsigned short)(kk.x >> 16));
        float k2 = bf2f((unsigned short)(kk.y & 0xffff)), k3 = bf2f((unsigned short)(kk.y >> 16));
        float p = qv.x * k0 + qv.y * k1 + qv.z * k2 + qv.w * k3;
        p += __shfl_xor(p, 1);
        p += __shfl_xor(p, 2);
        float logit = p * 0.25f;
        float mnew = fmaxf(mm, logit);
        float sc = __expf(mm - mnew);
        float w = __expf(logit - mnew);
        float v0 = bf2f((unsigned short)(vv.x & 0xffff)), v1 = bf2f((unsigned short)(vv.x >> 16));
        float v2 = bf2f((unsigned short)(vv.y & 0xffff)), v3 = bf2f((unsigned short)(vv.y >> 16));
        a0 = a0 * sc + w * v0;
        a1 = a1 * sc + w * v1;
        a2 = a2 * sc + w * v2;
        a3 = a3 * sc + w * v3;
        lac = lac * sc + w;
        mm = mnew;
    }
    float mo = __shfl_xor(mm, 32), lo = __shfl_xor(lac, 32);
    float b0 = __shfl_xor(a0, 32), b1 = __shfl_xor(a1, 32);
    float b2 = __shfl_xor(a2, 32), b3 = __shfl_xor(a3, 32);
    float ms = fmaxf(mm, mo);
    float s0 = __expf(mm - ms), s1 = __expf(mo - ms);
    a0 = a0 * s0 + b0 * s1;
    a1 = a1 * s0 + b1 * s1;
    a2 = a2 * s0 + b2 * s1;
    a3 = a3 * s0 + b3 * s1;
    lac = lac * s0 + lo * s1;
    float inv = 1.f / (lac + 1e-16f);
    float o0 = a0 * inv, o1 = a1 * inv, o2 = a2 * inv, o3 = a3 * inv;
    float4 rv = *(const float4*)(qs + (size_t)i * 256 + 128 + d0);
    float part = o0 * Wb[d0] + o1 * Wb[d0 + 1] + o2 * Wb[d0 + 2] + o3 * Wb[d0 + 3]
               + rv.x * Wb[128 + d0] + rv.y * Wb[128 + d0 + 1]
               + rv.z * Wb[128 + d0 + 2] + rv.w * Wb[128 + d0 + 3]
               + (o0 - rv.x) * Wb[256 + d0] + (o1 - rv.y) * Wb[256 + d0 + 1]
               + (o2 - rv.z) * Wb[256 + d0 + 2] + (o3 - rv.w) * Wb[256 + d0 + 3];
    if (g) part = 0.f;
#pragma unroll
    for (int msk = 1; msk <= 32; msk <<= 1) part += __shfl_xor(part, msk);
    float gg = 1.f / (1.f + __expf(-part));
    if (g == 0) {
        float4 o4 = {gg * rv.x + (1.f - gg) * o0, gg * rv.y + (1.f - gg) * o1,
                     gg * rv.z + (1.f - gg) * o2, gg * rv.w + (1.f - gg) * o3};
        *(float4*)(out + (size_t)i * HIDDIM + d0) = o4;
    }
}

// ---------------- attention layer 3: 4 edge slots x 16 lanes x 8 dims ----------------
// writes oslice[y][i][dims], oslice = per-pass base of [4][N][128]
__global__ __launch_bounds__(64) void attn_big_kernel(
    const float* __restrict__ q3, const unsigned short* __restrict__ kv3,
    const int* __restrict__ offs, const int* __restrict__ csr_src,
    float* __restrict__ oslice) {
    int i = blockIdx.x;
    int y = blockIdx.y;
    int l = threadIdx.x;
    int g = l >> 4;
    int s = l & 15;
    const float* qp = q3 + (size_t)i * 512 + y * 128 + 8 * s;
    float4 qa = *(const float4*)qp;
    float4 qb = *(const float4*)(qp + 4);
    int e0 = offs[i], e1 = offs[i + 1];
    float mm = -1e30f, lac = 0.f;
    float ac[8];
#pragma unroll
    for (int j = 0; j < 8; ++j) ac[j] = 0.f;
    for (int e = e0 + g; e < e1; e += 4) {
        int sn = csr_src[e];
        const unsigned short* row = kv3 + (size_t)sn * 1024 + y * 256 + 8 * s;
        uint4 kk = *(const uint4*)row;
        uint4 vv = *(const uint4*)(row + 128);
        float k0 = bf2f((unsigned short)(kk.x & 0xffff)), k1 = bf2f((unsigned short)(kk.x >> 16));
        float k2 = bf2f((unsigned short)(kk.y & 0xffff)), k3 = bf2f((unsigned short)(kk.y >> 16));
        float k4 = bf2f((unsigned short)(kk.z & 0xffff)), k5 = bf2f((unsigned short)(kk.z >> 16));
        float k6 = bf2f((unsigned short)(kk.w & 0xffff)), k7 = bf2f((unsigned short)(kk.w >> 16));
        float p = qa.x * k0 + qa.y * k1 + qa.z * k2 + qa.w * k3
                + qb.x * k4 + qb.y * k5 + qb.z * k6 + qb.w * k7;
        p += __shfl_xor(p, 1);
        p += __shfl_xor(p, 2);
        p += __shfl_xor(p, 4);
        p += __shfl_xor(p, 8);
        float logit = p * 0.08838834764831845f;
        float mnew = fmaxf(mm, logit);
        float sc = __expf(mm - mnew);
        float w = __expf(logit - mnew);
        float v0 = bf2f((unsigned short)(vv.x & 0xffff)), v1 = bf2f((unsigned short)(vv.x >> 16));
        float v2 = bf2f((unsigned short)(vv.y & 0xffff)), v3 = bf2f((unsigned short)(vv.y >> 16));
        float v4 = bf2f((unsigned short)(vv.z & 0xffff)), v5 = bf2f((unsigned short)(vv.z >> 16));
        float v6 = bf2f((unsigned short)(vv.w & 0xffff)), v7 = bf2f((unsigned short)(vv.w >> 16));
        ac[0] = ac[0] * sc + w * v0; ac[1] = ac[1] * sc + w * v1;
        ac[2] = ac[2] * sc + w * v2; ac[3] = ac[3] * sc + w * v3;
        ac[4] = ac[4] * sc + w * v4; ac[5] = ac[5] * sc + w * v5;
        ac[6] = ac[6] * sc + w * v6; ac[7] = ac[7] * sc + w * v7;
        lac = lac * sc + w;
        mm = mnew;
    }
#pragma unroll
    for (int msk = 16; msk <= 32; msk <<= 1) {
        float mo = __shfl_xor(mm, msk), lo = __shfl_xor(lac, msk);
        float bo[8];
#pragma unroll
        for (int j = 0; j < 8; ++j) bo[j] = __shfl_xor(ac[j], msk);
        float ms = fmaxf(mm, mo);
        float s0 = __expf(mm - ms), s1 = __expf(mo - ms);
#pragma unroll
        for (int j = 0; j < 8; ++j) ac[j] = ac[j] * s0 + bo[j] * s1;
        lac = lac * s0 + lo * s1;
        mm = ms;
    }
    if (g == 0) {
        float inv = 1.f / (lac + 1e-16f);
        float4 w0 = {ac[0] * inv, ac[1] * inv, ac[2] * inv, ac[3] * inv};
        float4 w1 = {ac[4] * inv, ac[5] * inv, ac[6] * inv, ac[7] * inv};
        float* o = oslice + ((size_t)y * NNODES + i) * HIDDIM + 8 * s;
        *(float4*)o = w0;
        *(float4*)(o + 4) = w1;
    }
}

// ---------------- beta gate layer 3 (head mean over 8 slices) ----------------
__global__ __launch_bounds__(128) void beta3_kernel(const float* __restrict__ obuf8,
                                                    const float* __restrict__ s,
                                                    const float* __restrict__ Wb,
                                                    float* __restrict__ out) {
    int i = blockIdx.x, t = threadIdx.x;
    float o = 0.f;
#pragma unroll
    for (int y = 0; y < 8; ++y) o += obuf8[((size_t)y * NNODES + i) * HIDDIM + t];
    o *= 0.125f;
    float r = s[(size_t)i * HIDDIM + t];
    float part = o * Wb[t] + r * Wb[128 + t] + (o - r) * Wb[256 + t];
#pragma unroll
    for (int msk = 1; msk <= 32; msk <<= 1) part += __shfl_xor(part, msk);
    __shared__ float wsum[2];
    if ((t & 63) == 0) wsum[t >> 6] = part;
    __syncthreads();
    float tot = wsum[0] + wsum[1];
    float g = 1.f / (1.f + __expf(-tot));
    out[(size_t)i * HIDDIM + t] = g * r + (1.f - g) * o;
}

// ---------------- batchnorm ----------------
__global__ __launch_bounds__(128) void bn_stats_kernel(const float* __restrict__ x,
                                                       float* __restrict__ stat, int n) {
    int t = threadIdx.x;
    float s = 0.f, sq = 0.f;
    for (int i = blockIdx.x; i < n; i += gridDim.x) {
        float v = x[(size_t)i * HIDDIM + t];
        s += v;
        sq += v * v;
    }
    atomicAdd(&stat[t], s);
    atomicAdd(&stat[HIDDIM + t], sq);
}

__global__ __launch_bounds__(128) void bn_apply_kernel(float* __restrict__ x,
                                                       const float* __restrict__ stat,
                                                       const float* __restrict__ gamma,
                                                       const float* __restrict__ beta, int n,
                                                       unsigned short* __restrict__ cat) {
    int t = threadIdx.x;
    float mu = stat[t] / (float)n;
    float var = stat[HIDDIM + t] / (float)n - mu * mu;
    float rs = rsqrtf(var + 1e-5f);
    float g = gamma[t], b = beta[t];
    for (int i = blockIdx.x; i < n; i += gridDim.x) {
        float v = x[(size_t)i * HIDDIM + t];
        v = fmaxf((v - mu) * rs * g + b, 0.f);
        x[(size_t)i * HIDDIM + t] = v;
        if (cat) {
            unsigned short hi = f2bf(v);
            unsigned short lo = f2bf(v - bf2f(hi));
            unsigned short* row = cat + (size_t)i * KC;
            row[t] = hi;
            row[128 + t] = lo;
            row[256 + t] = hi;
        }
    }
}

// ---------------- pool ----------------
__global__ __launch_bounds__(256) void gb_kernel(const int* __restrict__ batch,
                                                 int* __restrict__ gs,
                                                 int* __restrict__ ge, int n) {
    int i = blockIdx.x * 256 + threadIdx.x;
    if (i >= n) return;
    int b = batch[i];
    if (i == 0 || batch[i - 1] != b) gs[b] = i;
    if (i == n - 1 || batch[i + 1] != b) ge[b] = i + 1;
}

__global__ __launch_bounds__(256) void pool_part_kernel(const float* __restrict__ x,
                                                        const int* __restrict__ gs,
                                                        const int* __restrict__ ge,
                                                        float* __restrict__ out) {
    int g = blockIdx.x, c = blockIdx.y;
    int t = threadIdx.x;
    int f = t & 127, half = t >> 7;
    int s = gs[g], e = ge[g];
    float acc = 0.f;
    for (int i = s + 2 * c + half; i < e; i += 16) acc += x[(size_t)i * HIDDIM + f];
    __shared__ float l0[128];
    if (half == 0) l0[f] = acc;
    __syncthreads();
    if (half == 1) atomicAdd(&out[g * HIDDIM + f], l0[f] + acc);
}

__global__ __launch_bounds__(128) void pool_div_kernel(float* __restrict__ out,
                                                       const int* __restrict__ gs,
                                                       const int* __restrict__ ge) {
    int g = blockIdx.x, t = threadIdx.x;
    int c = ge[g] - gs[g];
    out[g * HIDDIM + t] /= (float)(c > 0 ? c : 1);
}

// ---------------- host ----------------
extern "C" void kernel_launch(void* const* d_in, const int* in_sizes, int n_in,
                              void* d_out, int out_size, void* d_ws, size_t ws_size,
                              hipStream_t stream) {
    const float* x       = (const float*)d_in[0];
    const int*   ei      = (const int*)d_in[1];
    const int*   batch   = (const int*)d_in[2];
    const float* Wp      = (const float*)d_in[3];
    const float* bp      = (const float*)d_in[4];
    const float* Wq      = (const float*)d_in[5];
    const float* bq      = (const float*)d_in[6];
    const float* Wk      = (const float*)d_in[7];
    const float* bk      = (const float*)d_in[8];
    const float* Wv      = (const float*)d_in[9];
    const float* bv      = (const float*)d_in[10];
    const float* Ws      = (const float*)d_in[11];
    const float* bs      = (const float*)d_in[12];
    const float* Wbeta   = (const float*)d_in[13];
    const float* Wq3     = (const float*)d_in[14];
    const float* bq3     = (const float*)d_in[15];
    const float* Wk3     = (const float*)d_in[16];
    const float* bk3     = (const float*)d_in[17];
    const float* Wv3     = (const float*)d_in[18];
    const float* bv3     = (const float*)d_in[19];
    const float* Ws3     = (const float*)d_in[20];
    const float* bs3     = (const float*)d_in[21];
    const float* Wbeta3  = (const float*)d_in[22];
    const float* bn_gamma = (const float*)d_in[23];
    const float* bn_beta  = (const float*)d_in[24];
    float* out = (float*)d_out;

    const int* esrc = ei;
    const int* edst = ei + NEDGES;

    char* wpc = (char*)d_ws;
    auto alloc = [&](size_t nbytes) -> char* {
        char* p = wpc;
        wpc += (nbytes + 255) & ~(size_t)255;
        return p;
    };
    unsigned short* Acat  = (unsigned short*)alloc((size_t)NPAD * KC * 2);
    unsigned short* WtAll = (unsigned short*)alloc((size_t)4864 * KC * 2);
    float* bcat   = (float*)alloc(4608 * 4);
    float* qsbuf  = (float*)alloc((size_t)NNODES * 512 * 4);
    unsigned short* kvbuf = (unsigned short*)alloc((size_t)NNODES * 1024 * 2);
    float* obuf8  = (float*)alloc((size_t)8 * NNODES * HIDDIM * 4);
    float* hbuf   = (float*)alloc((size_t)NNODES * HIDDIM * 4);
    float* obuf   = (float*)alloc((size_t)NNODES * HIDDIM * 4);
    float* sb     = (float*)alloc((size_t)NNODES * HIDDIM * 4);
    int*   deg    = (int*)alloc((2 * NNODES + 128 + 4 * 256) * 4);
    int*   cursor = deg + NNODES;
    int*   gs     = deg + 2 * NNODES;
    int*   ge     = gs + NGRAPH;
    float* bnstat4 = (float*)(deg + 2 * NNODES + 128);
    int*   chunk  = (int*)alloc(NNODES * 4);
    int*   bsum   = (int*)alloc(128 * 4);
    int*   offs   = (int*)alloc((NNODES + 1) * 4);
    int*   csrsrc = (int*)alloc(NEDGES * 4);

    unsigned short* WtL   = WtAll;
    unsigned short* Wpt   = WtAll + (size_t)1536 * KC;
    unsigned short* Ws3t  = WtAll + (size_t)1664 * KC;
    unsigned short* Wt3q  = WtAll + (size_t)1792 * KC;
    unsigned short* Wt3kv = WtAll + (size_t)2816 * KC;
    float* bcatL = bcat;
    float* b3q   = bcat + 1536;
    float* b3kv  = bcat + 2560;

    const int TB = 256;
    const int ZWORDS = 2 * NNODES + 128 + 4 * 256;
    zero_kernel<<<(ZWORDS + TB - 1) / TB, TB, 0, stream>>>((float*)deg, ZWORDS);
    count_deg_kernel<<<(NEDGES + TB - 1) / TB, TB, 0, stream>>>(edst, deg, NEDGES);
    const int NB = (NNODES + 255) / 256;
    scan1_kernel<<<NB, 256, 0, stream>>>(deg, chunk, bsum, NNODES);
    scan2_kernel<<<1, 128, 0, stream>>>(bsum, NB);
    scan3_kernel<<<NB, 256, 0, stream>>>(chunk, bsum, offs, NNODES);
    scatter_kernel<<<(NEDGES + TB - 1) / TB, TB, 0, stream>>>(esrc, edst, offs, cursor, csrsrc, NEDGES);
    gb_kernel<<<(NNODES + TB - 1) / TB, TB, 0, stream>>>(batch, gs, ge, NNODES);

    prep_w_kernel<<<4864, 128, 0, stream>>>(Wq, Wk, Wv, Ws, Wp, Ws3, Wq3, Wk3, Wv3, WtAll);
    prep_bias_kernel<<<(4608 + TB - 1) / TB, TB, 0, stream>>>(bq, bk, bv, bs, bq3, bk3, bv3, bcat);

    const int CATB = (NPAD * HIDDIM + TB - 1) / TB;
    const int GX = NPAD / 128;  // 157

    cat_from_kernel<<<CATB, TB, 0, stream>>>(x, Acat);
    gemm_mfma_kernel<float, 12><<<dim3(1, GX), 256, 0, stream>>>(Acat, Wpt, bp, hbuf, 128, NNODES);
    cat_from_kernel<<<CATB, TB, 0, stream>>>(hbuf, Acat);

    for (int li = 0; li < 3; ++li) {
        const unsigned short* Wl = WtL + (size_t)li * 512 * KC;
        gemm_mfma_kernel<float, 12><<<dim3(2, GX), 256, 0, stream>>>(
            Acat, Wl, bcatL + li * 512, qsbuf, 256, NNODES);
        gemm_mfma_kernel<unsigned short, 8><<<dim3(2, GX), 256, 0, stream>>>(
            Acat, Wl + (size_t)256 * KC, bcatL + li * 512 + 256, kvbuf, 256, NNODES);
        attn_small_kernel<<<NNODES, 64, 0, stream>>>(qsbuf, kvbuf, Wbeta + li * 384,
                                                     offs, csrsrc, obuf);
        float* st = bnstat4 + li * 256;
        bn_stats_kernel<<<640, 128, 0, stream>>>(obuf, st, NNODES);
        bn_apply_kernel<<<512, 128, 0, stream>>>(obuf, st, bn_gamma + li * HIDDIM,
                                                 bn_beta + li * HIDDIM, NNODES, Acat);
    }

    for (int h2 = 0; h2 < 2; ++h2) {
        gemm_mfma_kernel<float, 12><<<dim3(4, GX), 256, 0, stream>>>(
            Acat, Wt3q + (size_t)h2 * 512 * KC, b3q + h2 * 512, qsbuf, 512, NNODES);
        gemm_mfma_kernel<unsigned short, 8><<<dim3(8, GX), 256, 0, stream>>>(
            Acat, Wt3kv + (size_t)h2 * 1024 * KC, b3kv + h2 * 1024, kvbuf, 1024, NNODES);
        attn_big_kernel<<<dim3(NNODES, 4), 64, 0, stream>>>(
            qsbuf, kvbuf, offs, csrsrc, obuf8 + (size_t)h2 * 4 * NNODES * HIDDIM);
    }
    gemm_mfma_kernel<float, 12><<<dim3(1, GX), 256, 0, stream>>>(Acat, Ws3t, bs3, sb, 128, NNODES);
    beta3_kernel<<<NNODES, 128, 0, stream>>>(obuf8, sb, Wbeta3, hbuf);
    float* st3 = bnstat4 + 3 * 256;
    bn_stats_kernel<<<640, 128, 0, stream>>>(hbuf, st3, NNODES);
    bn_apply_kernel<<<512, 128, 0, stream>>>(hbuf, st3, bn_gamma + 3 * HIDDIM,
                                             bn_beta + 3 * HIDDIM, NNODES, (unsigned short*)0);

    zero_kernel<<<(NGRAPH * HIDDIM + TB - 1) / TB, TB, 0, stream>>>(out, NGRAPH * HIDDIM);
    pool_part_kernel<<<dim3(NGRAPH, 8), 256, 0, stream>>>(hbuf, gs, ge, out);
    pool_div_kernel<<<NGRAPH, 128, 0, stream>>>(out, gs, ge);
}

// Round 6
// 822.419 us; speedup vs baseline: 3.2032x; 1.0760x over previous
//
#include <hip/hip_runtime.h>
#include <math.h>

#define NNODES 20000
#define NPAD   20096   // 157 * 128
#define NEDGES 160000
#define HIDDIM 128
#define NHEADS 8
#define NGRAPH 64
#define KC 384   // concatenated K (hi | lo | hi)

typedef short short8 __attribute__((ext_vector_type(8)));
typedef float floatx4 __attribute__((ext_vector_type(4)));
typedef unsigned short ushort4v __attribute__((ext_vector_type(4)));

__device__ inline unsigned short f2bf(float x) {
    unsigned u = __float_as_uint(x);
    u += 0x7fff + ((u >> 16) & 1);
    return (unsigned short)(u >> 16);
}
__device__ inline float bf2f(unsigned short h) {
    return __uint_as_float(((unsigned)h) << 16);
}

// ---------------- utility ----------------
__global__ __launch_bounds__(256) void zero_kernel(float* __restrict__ p, int n) {
    int i = blockIdx.x * blockDim.x + threadIdx.x;
    if (i < n) p[i] = 0.f;
}

// ---------------- CSR build ----------------
__global__ __launch_bounds__(256) void count_deg_kernel(const int* __restrict__ dst,
                                                        int* __restrict__ deg, int e) {
    int i = blockIdx.x * blockDim.x + threadIdx.x;
    if (i < e) atomicAdd(&deg[dst[i]], 1);
}

__global__ __launch_bounds__(256) void scan1_kernel(const int* __restrict__ deg,
                                                    int* __restrict__ chunk,
                                                    int* __restrict__ bsum, int n) {
    __shared__ int buf[256];
    int t = threadIdx.x;
    int i = blockIdx.x * 256 + t;
    int v = (i < n) ? deg[i] : 0;
    buf[t] = v;
    __syncthreads();
    for (int off = 1; off < 256; off <<= 1) {
        int tmp = (t >= off) ? buf[t - off] : 0;
        __syncthreads();
        buf[t] += tmp;
        __syncthreads();
    }
    if (i < n) chunk[i] = buf[t];
    if (t == 255) bsum[blockIdx.x] = buf[255];
}

__global__ __launch_bounds__(128) void scan2_kernel(int* __restrict__ bsum, int nb) {
    __shared__ int buf[128];
    int t = threadIdx.x;
    int v = (t < nb) ? bsum[t] : 0;
    buf[t] = v;
    __syncthreads();
    for (int off = 1; off < 128; off <<= 1) {
        int tmp = (t >= off) ? buf[t - off] : 0;
        __syncthreads();
        buf[t] += tmp;
        __syncthreads();
    }
    if (t < nb) bsum[t] = buf[t] - v;
}

__global__ __launch_bounds__(256) void scan3_kernel(const int* __restrict__ chunk,
                                                    const int* __restrict__ bsum,
                                                    int* __restrict__ offs, int n) {
    int i = blockIdx.x * 256 + threadIdx.x;
    if (i < n) offs[i + 1] = chunk[i] + bsum[i >> 8];
    if (i == 0) offs[0] = 0;
}

__global__ __launch_bounds__(256) void scatter_kernel(const int* __restrict__ src,
                                                      const int* __restrict__ dst,
                                                      const int* __restrict__ offs,
                                                      int* __restrict__ cursor,
                                                      int* __restrict__ csr_src, int e) {
    int i = blockIdx.x * blockDim.x + threadIdx.x;
    if (i < e) {
        int d = dst[i];
        int pos = offs[d] + atomicAdd(&cursor[d], 1);
        csr_src[pos] = src[i];
    }
}

// ---------------- weight prep ----------------
__global__ __launch_bounds__(128) void prep_w_kernel(
    const float* __restrict__ Wq, const float* __restrict__ Wk,
    const float* __restrict__ Wv, const float* __restrict__ Ws,
    const float* __restrict__ Wp, const float* __restrict__ Ws3,
    const float* __restrict__ Wq3, const float* __restrict__ Wk3,
    const float* __restrict__ Wv3, unsigned short* __restrict__ WtAll) {
    int id = blockIdx.x;
    int k = threadIdx.x;
    float w;
    if (id < 1536) {
        int li = id / 512, n = id % 512, sel = n >> 7, np = n & 127;
        const float* W = (sel == 0) ? Wq : (sel == 1) ? Ws : (sel == 2) ? Wk : Wv;
        w = W[li * 16384 + k * 128 + np];
    } else if (id < 1664) {
        w = Wp[k * 128 + (id - 1536)];
    } else if (id < 1792) {
        w = Ws3[k * 128 + (id - 1664)];
    } else if (id < 2816) {
        int r = id - 1792, h = r >> 7, j = r & 127;
        w = Wq3[k * 1024 + h * 128 + j];
    } else {
        int r = id - 2816, h = r >> 8, jj = r & 255;
        const float* W = (jj < 128) ? Wk3 : Wv3;
        w = W[k * 1024 + h * 128 + (jj & 127)];
    }
    unsigned short hi = f2bf(w);
    unsigned short lo = f2bf(w - bf2f(hi));
    unsigned short* dst = WtAll + (size_t)id * KC;
    dst[k] = hi;
    dst[128 + k] = hi;
    dst[256 + k] = lo;
}

__global__ __launch_bounds__(256) void prep_bias_kernel(
    const float* __restrict__ bq, const float* __restrict__ bk,
    const float* __restrict__ bv, const float* __restrict__ bs,
    const float* __restrict__ bq3, const float* __restrict__ bk3,
    const float* __restrict__ bv3, float* __restrict__ bcat) {
    int id = blockIdx.x * 256 + threadIdx.x;
    if (id >= 4608) return;
    float v;
    if (id < 1536) {
        int li = id / 512, n = id % 512, sel = n >> 7, np = n & 127;
        const float* b = (sel == 0) ? bq : (sel == 1) ? bs : (sel == 2) ? bk : bv;
        v = b[li * 128 + np];
    } else if (id < 2560) {
        v = bq3[id - 1536];
    } else {
        int r = id - 2560, h = r >> 8, jj = r & 255;
        const float* b = (jj < 128) ? bk3 : bv3;
        v = b[h * 128 + (jj & 127)];
    }
    bcat[id] = v;
}

// ---------------- activation -> split-bf16 A_cat ----------------
__global__ __launch_bounds__(256) void cat_from_kernel(const float* __restrict__ h,
                                                       unsigned short* __restrict__ Acat) {
    int idx = blockIdx.x * 256 + threadIdx.x;
    if (idx >= NPAD * HIDDIM) return;
    int r = idx >> 7, k = idx & 127;
    float x = (r < NNODES) ? h[idx] : 0.f;
    unsigned short hi = f2bf(x);
    unsigned short lo = f2bf(x - bf2f(hi));
    unsigned short* row = Acat + (size_t)r * KC;
    row[k] = hi;
    row[128 + k] = lo;
    row[256 + k] = hi;
}

// ---------------- MFMA GEMM ----------------
// A-frag = Wt rows (features), B-frag = Acat rows (nodes): each acc quad then
// holds 4 CONSECUTIVE FEATURES of one node -> vectorized epilogue stores.
// grid (NPAD/128, M/128) row-fast. 4 waves, each a 64(node)x64(feat) patch.
template <typename OutT, int KG>
__global__ __launch_bounds__(256) void gemm_mfma_kernel(
    const unsigned short* __restrict__ Acat, const unsigned short* __restrict__ Wt,
    const float* __restrict__ bias, OutT* __restrict__ C, int M, int nrows) {
    int lane = threadIdx.x & 63;
    int wave = threadIdx.x >> 6;
    int nodeBase = blockIdx.x * 128 + (wave & 1) * 64;
    int featBase = blockIdx.y * 128 + (wave >> 1) * 64;
    int m = lane & 15;
    int q = lane >> 4;
    int ko = q * 8;
    const unsigned short* wptr = Wt + (size_t)(featBase + m) * KC + ko;    // A operand
    const unsigned short* aptr = Acat + (size_t)(nodeBase + m) * KC + ko;  // B operand
    floatx4 acc[4][4];  // [feat tile r][node tile c]
#pragma unroll
    for (int r = 0; r < 4; ++r)
#pragma unroll
        for (int c = 0; c < 4; ++c) acc[r][c] = (floatx4){0.f, 0.f, 0.f, 0.f};
#pragma unroll
    for (int kg = 0; kg < KG; ++kg) {
        short8 a[4], b[4];
#pragma unroll
        for (int r = 0; r < 4; ++r) a[r] = *(const short8*)(wptr + (size_t)r * 16 * KC + kg * 32);
#pragma unroll
        for (int c = 0; c < 4; ++c) b[c] = *(const short8*)(aptr + (size_t)c * 16 * KC + kg * 32);
#pragma unroll
        for (int r = 0; r < 4; ++r)
#pragma unroll
            for (int c = 0; c < 4; ++c)
                acc[r][c] = __builtin_amdgcn_mfma_f32_16x16x32_bf16(a[r], b[c], acc[r][c], 0, 0, 0);
    }
#pragma unroll
    for (int r = 0; r < 4; ++r) {
        int f0 = featBase + r * 16 + q * 4;
        float4 bv = *(const float4*)(bias + f0);
#pragma unroll
        for (int c = 0; c < 4; ++c) {
            int node = nodeBase + c * 16 + m;
            if (node < nrows) {
                float v0 = acc[r][c][0] + bv.x;
                float v1 = acc[r][c][1] + bv.y;
                float v2 = acc[r][c][2] + bv.z;
                float v3 = acc[r][c][3] + bv.w;
                if (sizeof(OutT) == 2) {
                    ushort4v o = {f2bf(v0), f2bf(v1), f2bf(v2), f2bf(v3)};
                    *(ushort4v*)((unsigned short*)C + (size_t)node * M + f0) = o;
                } else {
                    float4 o = {v0, v1, v2, v3};
                    *(float4*)((float*)C + (size_t)node * M + f0) = o;
                }
            }
        }
    }
}

// ---------------- attention layers 0-2: 2 edge slots x (8 heads x 4 lanes) ----------------
__global__ __launch_bounds__(64) void attn_small_kernel(
    const float* __restrict__ qs, const unsigned short* __restrict__ kv,
    const float* __restrict__ Wb,
    const int* __restrict__ offs, const int* __restrict__ csr_src,
    float* __restrict__ out) {
    int i = blockIdx.x;
    int l = threadIdx.x;
    int g = l >> 5;
    int d0 = (l & 31) * 4;
    float4 qv = *(const float4*)(qs + (size_t)i * 256 + d0);
    int e0 = offs[i], e1 = offs[i + 1];
    float mm = -1e30f, lac = 0.f;
    float a0 = 0.f, a1 = 0.f, a2 = 0.f, a3 = 0.f;
    for (int e = e0 + g; e < e1; e += 2) {
        int sn = csr_src[e];
        const unsigned short* row = kv + (size_t)sn * 256;
        uint2 kk = *(const uint2*)(row + d0);
        uint2 vv = *(const uint2*)(row + 128 + d0);
        float k0 = bf2f((unsigned short)(kk.x & 0xffff)), k1 = bf2f((unsigned short)(kk.x >> 16));
        float k2 = bf2f((unsigned short)(kk.y & 0xffff)), k3 = bf2f((unsigned short)(kk.y >> 16));
        float p = qv.x * k0 + qv.y * k1 + qv.z * k2 + qv.w * k3;
        p += __shfl_xor(p, 1);
        p += __shfl_xor(p, 2);
        float logit = p * 0.25f;
        float mnew = fmaxf(mm, logit);
        float sc = __expf(mm - mnew);
        float w = __expf(logit - mnew);
        float v0 = bf2f((unsigned short)(vv.x & 0xffff)), v1 = bf2f((unsigned short)(vv.x >> 16));
        float v2 = bf2f((unsigned short)(vv.y & 0xffff)), v3 = bf2f((unsigned short)(vv.y >> 16));
        a0 = a0 * sc + w * v0;
        a1 = a1 * sc + w * v1;
        a2 = a2 * sc + w * v2;
        a3 = a3 * sc + w * v3;
        lac = lac * sc + w;
        mm = mnew;
    }
    float mo = __shfl_xor(mm, 32), lo = __shfl_xor(lac, 32);
    float b0 = __shfl_xor(a0, 32), b1 = __shfl_xor(a1, 32);
    float b2 = __shfl_xor(a2, 32), b3 = __shfl_xor(a3, 32);
    float ms = fmaxf(mm, mo);
    float s0 = __expf(mm - ms), s1 = __expf(mo - ms);
    a0 = a0 * s0 + b0 * s1;
    a1 = a1 * s0 + b1 * s1;
    a2 = a2 * s0 + b2 * s1;
    a3 = a3 * s0 + b3 * s1;
    lac = lac * s0 + lo * s1;
    float inv = 1.f / (lac + 1e-16f);
    float o0 = a0 * inv, o1 = a1 * inv, o2 = a2 * inv, o3 = a3 * inv;
    float4 rv = *(const float4*)(qs + (size_t)i * 256 + 128 + d0);
    float part = o0 * Wb[d0] + o1 * Wb[d0 + 1] + o2 * Wb[d0 + 2] + o3 * Wb[d0 + 3]
               + rv.x * Wb[128 + d0] + rv.y * Wb[128 + d0 + 1]
               + rv.z * Wb[128 + d0 + 2] + rv.w * Wb[128 + d0 + 3]
               + (o0 - rv.x) * Wb[256 + d0] + (o1 - rv.y) * Wb[256 + d0 + 1]
               + (o2 - rv.z) * Wb[256 + d0 + 2] + (o3 - rv.w) * Wb[256 + d0 + 3];
    if (g) part = 0.f;
#pragma unroll
    for (int msk = 1; msk <= 32; msk <<= 1) part += __shfl_xor(part, msk);
    float gg = 1.f / (1.f + __expf(-part));
    if (g == 0) {
        float4 o4 = {gg * rv.x + (1.f - gg) * o0, gg * rv.y + (1.f - gg) * o1,
                     gg * rv.z + (1.f - gg) * o2, gg * rv.w + (1.f - gg) * o3};
        *(float4*)(out + (size_t)i * HIDDIM + d0) = o4;
    }
}

// ---------------- attention layer 3: 4 edge slots x 16 lanes x 8 dims ----------------
__global__ __launch_bounds__(64) void attn_big_kernel(
    const float* __restrict__ q3, const unsigned short* __restrict__ kv3,
    const int* __restrict__ offs, const int* __restrict__ csr_src,
    float* __restrict__ oslice) {
    int i = blockIdx.x;
    int y = blockIdx.y;
    int l = threadIdx.x;
    int g = l >> 4;
    int s = l & 15;
    const float* qp = q3 + (size_t)i * 512 + y * 128 + 8 * s;
    float4 qa = *(const float4*)qp;
    float4 qb = *(const float4*)(qp + 4);
    int e0 = offs[i], e1 = offs[i + 1];
    float mm = -1e30f, lac = 0.f;
    float ac[8];
#pragma unroll
    for (int j = 0; j < 8; ++j) ac[j] = 0.f;
    for (int e = e0 + g; e < e1; e += 4) {
        int sn = csr_src[e];
        const unsigned short* row = kv3 + (size_t)sn * 1024 + y * 256 + 8 * s;
        uint4 kk = *(const uint4*)row;
        uint4 vv = *(const uint4*)(row + 128);
        float k0 = bf2f((unsigned short)(kk.x & 0xffff)), k1 = bf2f((unsigned short)(kk.x >> 16));
        float k2 = bf2f((unsigned short)(kk.y & 0xffff)), k3 = bf2f((unsigned short)(kk.y >> 16));
        float k4 = bf2f((unsigned short)(kk.z & 0xffff)), k5 = bf2f((unsigned short)(kk.z >> 16));
        float k6 = bf2f((unsigned short)(kk.w & 0xffff)), k7 = bf2f((unsigned short)(kk.w >> 16));
        float p = qa.x * k0 + qa.y * k1 + qa.z * k2 + qa.w * k3
                + qb.x * k4 + qb.y * k5 + qb.z * k6 + qb.w * k7;
        p += __shfl_xor(p, 1);
        p += __shfl_xor(p, 2);
        p += __shfl_xor(p, 4);
        p += __shfl_xor(p, 8);
        float logit = p * 0.08838834764831845f;
        float mnew = fmaxf(mm, logit);
        float sc = __expf(mm - mnew);
        float w = __expf(logit - mnew);
        float v0 = bf2f((unsigned short)(vv.x & 0xffff)), v1 = bf2f((unsigned short)(vv.x >> 16));
        float v2 = bf2f((unsigned short)(vv.y & 0xffff)), v3 = bf2f((unsigned short)(vv.y >> 16));
        float v4 = bf2f((unsigned short)(vv.z & 0xffff)), v5 = bf2f((unsigned short)(vv.z >> 16));
        float v6 = bf2f((unsigned short)(vv.w & 0xffff)), v7 = bf2f((unsigned short)(vv.w >> 16));
        ac[0] = ac[0] * sc + w * v0; ac[1] = ac[1] * sc + w * v1;
        ac[2] = ac[2] * sc + w * v2; ac[3] = ac[3] * sc + w * v3;
        ac[4] = ac[4] * sc + w * v4; ac[5] = ac[5] * sc + w * v5;
        ac[6] = ac[6] * sc + w * v6; ac[7] = ac[7] * sc + w * v7;
        lac = lac * sc + w;
        mm = mnew;
    }
#pragma unroll
    for (int msk = 16; msk <= 32; msk <<= 1) {
        float mo = __shfl_xor(mm, msk), lo = __shfl_xor(lac, msk);
        float bo[8];
#pragma unroll
        for (int j = 0; j < 8; ++j) bo[j] = __shfl_xor(ac[j], msk);
        float ms = fmaxf(mm, mo);
        float s0 = __expf(mm - ms), s1 = __expf(mo - ms);
#pragma unroll
        for (int j = 0; j < 8; ++j) ac[j] = ac[j] * s0 + bo[j] * s1;
        lac = lac * s0 + lo * s1;
        mm = ms;
    }
    if (g == 0) {
        float inv = 1.f / (lac + 1e-16f);
        float4 w0 = {ac[0] * inv, ac[1] * inv, ac[2] * inv, ac[3] * inv};
        float4 w1 = {ac[4] * inv, ac[5] * inv, ac[6] * inv, ac[7] * inv};
        float* o = oslice + ((size_t)y * NNODES + i) * HIDDIM + 8 * s;
        *(float4*)o = w0;
        *(float4*)(o + 4) = w1;
    }
}

// ---------------- beta gate layer 3 (head mean over 8 slices) ----------------
__global__ __launch_bounds__(128) void beta3_kernel(const float* __restrict__ obuf8,
                                                    const float* __restrict__ s,
                                                    const float* __restrict__ Wb,
                                                    float* __restrict__ out) {
    int i = blockIdx.x, t = threadIdx.x;
    float o = 0.f;
#pragma unroll
    for (int y = 0; y < 8; ++y) o += obuf8[((size_t)y * NNODES + i) * HIDDIM + t];
    o *= 0.125f;
    float r = s[(size_t)i * HIDDIM + t];
    float part = o * Wb[t] + r * Wb[128 + t] + (o - r) * Wb[256 + t];
#pragma unroll
    for (int msk = 1; msk <= 32; msk <<= 1) part += __shfl_xor(part, msk);
    __shared__ float wsum[2];
    if ((t & 63) == 0) wsum[t >> 6] = part;
    __syncthreads();
    float tot = wsum[0] + wsum[1];
    float g = 1.f / (1.f + __expf(-tot));
    out[(size_t)i * HIDDIM + t] = g * r + (1.f - g) * o;
}

// ---------------- batchnorm ----------------
__global__ __launch_bounds__(128) void bn_stats_kernel(const float* __restrict__ x,
                                                       float* __restrict__ stat, int n) {
    int t = threadIdx.x;
    float s = 0.f, sq = 0.f;
    for (int i = blockIdx.x; i < n; i += gridDim.x) {
        float v = x[(size_t)i * HIDDIM + t];
        s += v;
        sq += v * v;
    }
    atomicAdd(&stat[t], s);
    atomicAdd(&stat[HIDDIM + t], sq);
}

__global__ __launch_bounds__(128) void bn_apply_kernel(float* __restrict__ x,
                                                       const float* __restrict__ stat,
                                                       const float* __restrict__ gamma,
                                                       const float* __restrict__ beta, int n,
                                                       unsigned short* __restrict__ cat) {
    int t = threadIdx.x;
    float mu = stat[t] / (float)n;
    float var = stat[HIDDIM + t] / (float)n - mu * mu;
    float rs = rsqrtf(var + 1e-5f);
    float g = gamma[t], b = beta[t];
    for (int i = blockIdx.x; i < n; i += gridDim.x) {
        float v = x[(size_t)i * HIDDIM + t];
        v = fmaxf((v - mu) * rs * g + b, 0.f);
        x[(size_t)i * HIDDIM + t] = v;
        if (cat) {
            unsigned short hi = f2bf(v);
            unsigned short lo = f2bf(v - bf2f(hi));
            unsigned short* row = cat + (size_t)i * KC;
            row[t] = hi;
            row[128 + t] = lo;
            row[256 + t] = hi;
        }
    }
}

// ---------------- pool ----------------
__global__ __launch_bounds__(256) void gb_kernel(const int* __restrict__ batch,
                                                 int* __restrict__ gs,
                                                 int* __restrict__ ge, int n) {
    int i = blockIdx.x * 256 + threadIdx.x;
    if (i >= n) return;
    int b = batch[i];
    if (i == 0 || batch[i - 1] != b) gs[b] = i;
    if (i == n - 1 || batch[i + 1] != b) ge[b] = i + 1;
}

__global__ __launch_bounds__(256) void pool_part_kernel(const float* __restrict__ x,
                                                        const int* __restrict__ gs,
                                                        const int* __restrict__ ge,
                                                        float* __restrict__ out) {
    int g = blockIdx.x, c = blockIdx.y;
    int t = threadIdx.x;
    int f = t & 127, half = t >> 7;
    int s = gs[g], e = ge[g];
    float acc = 0.f;
    for (int i = s + 2 * c + half; i < e; i += 16) acc += x[(size_t)i * HIDDIM + f];
    __shared__ float l0[128];
    if (half == 0) l0[f] = acc;
    __syncthreads();
    if (half == 1) atomicAdd(&out[g * HIDDIM + f], l0[f] + acc);
}

__global__ __launch_bounds__(128) void pool_div_kernel(float* __restrict__ out,
                                                       const int* __restrict__ gs,
                                                       const int* __restrict__ ge) {
    int g = blockIdx.x, t = threadIdx.x;
    int c = ge[g] - gs[g];
    out[g * HIDDIM + t] /= (float)(c > 0 ? c : 1);
}

// ---------------- host ----------------
extern "C" void kernel_launch(void* const* d_in, const int* in_sizes, int n_in,
                              void* d_out, int out_size, void* d_ws, size_t ws_size,
                              hipStream_t stream) {
    const float* x       = (const float*)d_in[0];
    const int*   ei      = (const int*)d_in[1];
    const int*   batch   = (const int*)d_in[2];
    const float* Wp      = (const float*)d_in[3];
    const float* bp      = (const float*)d_in[4];
    const float* Wq      = (const float*)d_in[5];
    const float* bq      = (const float*)d_in[6];
    const float* Wk      = (const float*)d_in[7];
    const float* bk      = (const float*)d_in[8];
    const float* Wv      = (const float*)d_in[9];
    const float* bv      = (const float*)d_in[10];
    const float* Ws      = (const float*)d_in[11];
    const float* bs      = (const float*)d_in[12];
    const float* Wbeta   = (const float*)d_in[13];
    const float* Wq3     = (const float*)d_in[14];
    const float* bq3     = (const float*)d_in[15];
    const float* Wk3     = (const float*)d_in[16];
    const float* bk3     = (const float*)d_in[17];
    const float* Wv3     = (const float*)d_in[18];
    const float* bv3     = (const float*)d_in[19];
    const float* Ws3     = (const float*)d_in[20];
    const float* bs3     = (const float*)d_in[21];
    const float* Wbeta3  = (const float*)d_in[22];
    const float* bn_gamma = (const float*)d_in[23];
    const float* bn_beta  = (const float*)d_in[24];
    float* out = (float*)d_out;

    const int* esrc = ei;
    const int* edst = ei + NEDGES;

    char* wpc = (char*)d_ws;
    auto alloc = [&](size_t nbytes) -> char* {
        char* p = wpc;
        wpc += (nbytes + 255) & ~(size_t)255;
        return p;
    };
    unsigned short* Acat  = (unsigned short*)alloc((size_t)NPAD * KC * 2);
    unsigned short* WtAll = (unsigned short*)alloc((size_t)4864 * KC * 2);
    float* bcat   = (float*)alloc(4608 * 4);
    float* qsbuf  = (float*)alloc((size_t)NNODES * 512 * 4);
    unsigned short* kvbuf = (unsigned short*)alloc((size_t)NNODES * 1024 * 2);
    float* obuf8  = (float*)alloc((size_t)8 * NNODES * HIDDIM * 4);
    float* hbuf   = (float*)alloc((size_t)NNODES * HIDDIM * 4);
    float* obuf   = (float*)alloc((size_t)NNODES * HIDDIM * 4);
    float* sb     = (float*)alloc((size_t)NNODES * HIDDIM * 4);
    int*   deg    = (int*)alloc((2 * NNODES + 128 + 4 * 256) * 4);
    int*   cursor = deg + NNODES;
    int*   gs     = deg + 2 * NNODES;
    int*   ge     = gs + NGRAPH;
    float* bnstat4 = (float*)(deg + 2 * NNODES + 128);
    int*   chunk  = (int*)alloc(NNODES * 4);
    int*   bsum   = (int*)alloc(128 * 4);
    int*   offs   = (int*)alloc((NNODES + 1) * 4);
    int*   csrsrc = (int*)alloc(NEDGES * 4);

    unsigned short* WtL   = WtAll;
    unsigned short* Wpt   = WtAll + (size_t)1536 * KC;
    unsigned short* Ws3t  = WtAll + (size_t)1664 * KC;
    unsigned short* Wt3q  = WtAll + (size_t)1792 * KC;
    unsigned short* Wt3kv = WtAll + (size_t)2816 * KC;
    float* bcatL = bcat;
    float* b3q   = bcat + 1536;
    float* b3kv  = bcat + 2560;

    const int TB = 256;
    const int ZWORDS = 2 * NNODES + 128 + 4 * 256;
    zero_kernel<<<(ZWORDS + TB - 1) / TB, TB, 0, stream>>>((float*)deg, ZWORDS);
    count_deg_kernel<<<(NEDGES + TB - 1) / TB, TB, 0, stream>>>(edst, deg, NEDGES);
    const int NB = (NNODES + 255) / 256;
    scan1_kernel<<<NB, 256, 0, stream>>>(deg, chunk, bsum, NNODES);
    scan2_kernel<<<1, 128, 0, stream>>>(bsum, NB);
    scan3_kernel<<<NB, 256, 0, stream>>>(chunk, bsum, offs, NNODES);
    scatter_kernel<<<(NEDGES + TB - 1) / TB, TB, 0, stream>>>(esrc, edst, offs, cursor, csrsrc, NEDGES);
    gb_kernel<<<(NNODES + TB - 1) / TB, TB, 0, stream>>>(batch, gs, ge, NNODES);

    prep_w_kernel<<<4864, 128, 0, stream>>>(Wq, Wk, Wv, Ws, Wp, Ws3, Wq3, Wk3, Wv3, WtAll);
    prep_bias_kernel<<<(4608 + TB - 1) / TB, TB, 0, stream>>>(bq, bk, bv, bs, bq3, bk3, bv3, bcat);

    const int CATB = (NPAD * HIDDIM + TB - 1) / TB;
    const int GX = NPAD / 128;  // 157

    cat_from_kernel<<<CATB, TB, 0, stream>>>(x, Acat);
    gemm_mfma_kernel<float, 12><<<dim3(GX, 1), 256, 0, stream>>>(Acat, Wpt, bp, hbuf, 128, NNODES);
    cat_from_kernel<<<CATB, TB, 0, stream>>>(hbuf, Acat);

    for (int li = 0; li < 3; ++li) {
        const unsigned short* Wl = WtL + (size_t)li * 512 * KC;
        gemm_mfma_kernel<float, 12><<<dim3(GX, 2), 256, 0, stream>>>(
            Acat, Wl, bcatL + li * 512, qsbuf, 256, NNODES);
        gemm_mfma_kernel<unsigned short, 8><<<dim3(GX, 2), 256, 0, stream>>>(
            Acat, Wl + (size_t)256 * KC, bcatL + li * 512 + 256, kvbuf, 256, NNODES);
        attn_small_kernel<<<NNODES, 64, 0, stream>>>(qsbuf, kvbuf, Wbeta + li * 384,
                                                     offs, csrsrc, obuf);
        float* st = bnstat4 + li * 256;
        bn_stats_kernel<<<640, 128, 0, stream>>>(obuf, st, NNODES);
        bn_apply_kernel<<<512, 128, 0, stream>>>(obuf, st, bn_gamma + li * HIDDIM,
                                                 bn_beta + li * HIDDIM, NNODES, Acat);
    }

    for (int h2 = 0; h2 < 2; ++h2) {
        gemm_mfma_kernel<float, 12><<<dim3(GX, 4), 256, 0, stream>>>(
            Acat, Wt3q + (size_t)h2 * 512 * KC, b3q + h2 * 512, qsbuf, 512, NNODES);
        gemm_mfma_kernel<unsigned short, 8><<<dim3(GX, 8), 256, 0, stream>>>(
            Acat, Wt3kv + (size_t)h2 * 1024 * KC, b3kv + h2 * 1024, kvbuf, 1024, NNODES);
        attn_big_kernel<<<dim3(NNODES, 4), 64, 0, stream>>>(
            qsbuf, kvbuf, offs, csrsrc, obuf8 + (size_t)h2 * 4 * NNODES * HIDDIM);
    }
    gemm_mfma_kernel<float, 12><<<dim3(GX, 1), 256, 0, stream>>>(Acat, Ws3t, bs3, sb, 128, NNODES);
    beta3_kernel<<<NNODES, 128, 0, stream>>>(obuf8, sb, Wbeta3, hbuf);
    float* st3 = bnstat4 + 3 * 256;
    bn_stats_kernel<<<640, 128, 0, stream>>>(hbuf, st3, NNODES);
    bn_apply_kernel<<<512, 128, 0, stream>>>(hbuf, st3, bn_gamma + 3 * HIDDIM,
                                             bn_beta + 3 * HIDDIM, NNODES, (unsigned short*)0);

    zero_kernel<<<(NGRAPH * HIDDIM + TB - 1) / TB, TB, 0, stream>>>(out, NGRAPH * HIDDIM);
    pool_part_kernel<<<dim3(NGRAPH, 8), 256, 0, stream>>>(hbuf, gs, ge, out);
    pool_div_kernel<<<NGRAPH, 128, 0, stream>>>(out, gs, ge);
}